// Round 1
// baseline (245.266 us; speedup 1.0000x reference)
//
#include <hip/hip_runtime.h>
#include <math.h>

#define BB 8
#define NN 512
#define DD 1024
#define HH 16
#define DH 64
#define INNER 1024
#define QKV3 3072
// attn head-plane stride in shorts: N*N + 64 (128B pad) breaks the exact
// 512KB power-of-2 stride that aliases all 16 head planes onto the same
// L2-set/HBM-channel group in reattn_ln_bf's 16-plane gather.
#define PSTR (NN * NN + 64)

typedef __attribute__((ext_vector_type(8))) short short8;
typedef __attribute__((ext_vector_type(4))) float f32x4;

#define AS1 __attribute__((address_space(1)))
#define AS3 __attribute__((address_space(3)))

__device__ __forceinline__ float4 ld4(const float* p) { return *(const float4*)p; }

__device__ __forceinline__ unsigned short f2bf(float f) {
    unsigned u = __float_as_uint(f);
    return (unsigned short)((u + 0x7fffu + ((u >> 16) & 1u)) >> 16);
}
__device__ __forceinline__ float bf2f(unsigned short u) {
    return __uint_as_float(((unsigned)u) << 16);
}

// ---------------------------------------------------------------------------
// fp32 -> bf16 elementwise convert (4 els/thread)
// ---------------------------------------------------------------------------
__global__ void conv_bf16(const float* __restrict__ in, unsigned short* __restrict__ out) {
    size_t i = ((size_t)blockIdx.x * 256 + threadIdx.x) * 4;
    float4 v = ld4(in + i);
    ushort4 o;
    o.x = f2bf(v.x); o.y = f2bf(v.y); o.z = f2bf(v.z); o.w = f2bf(v.w);
    *(ushort4*)(out + i) = o;
}

// ---------------------------------------------------------------------------
// fp32 [K][N] -> bf16 [N][K] transpose-convert, 32x32 LDS tiles
// ---------------------------------------------------------------------------
__global__ void convT_bf16(const float* __restrict__ in, unsigned short* __restrict__ out,
                           int K, int N) {
    __shared__ float t[32][33];
    const int n0 = blockIdx.x * 32, k0 = blockIdx.y * 32;
    const int tx = threadIdx.x & 31, ty = threadIdx.x >> 5;  // 32 x 8
#pragma unroll
    for (int l = 0; l < 4; ++l)
        t[ty + 8 * l][tx] = in[(size_t)(k0 + ty + 8 * l) * N + n0 + tx];
    __syncthreads();
#pragma unroll
    for (int l = 0; l < 4; ++l)
        out[(size_t)(n0 + ty + 8 * l) * K + k0 + tx] = f2bf(t[tx][ty + 8 * l]);
}

// ---------------------------------------------------------------------------
// bf16 MFMA GEMM, fp32 out (+bias): C[M,N] = A[M,K] * Bt[N,K]^T
// ---------------------------------------------------------------------------
__global__ __launch_bounds__(256) void gemm_bf16(
    const unsigned short* __restrict__ A, const unsigned short* __restrict__ Bt,
    float* __restrict__ C, const float* __restrict__ bias, int M, int N, int K) {
    __shared__ short As[128 * 32];
    __shared__ short Bs[128 * 32];
    const int tid = threadIdx.x;
    const int w = tid >> 6, l = tid & 63;
    const int bm = blockIdx.y * 128, bn = blockIdx.x * 128;
    const int wm = (w >> 1) * 64, wn = (w & 1) * 64;
    const int lrow = l & 15, lq = l >> 4;

    f32x4 acc[4][4];
#pragma unroll
    for (int i = 0; i < 4; ++i)
#pragma unroll
        for (int j = 0; j < 4; ++j) acc[i][j] = (f32x4){0.f, 0.f, 0.f, 0.f};

    for (int k0 = 0; k0 < K; k0 += 32) {
#pragma unroll
        for (int t = 0; t < 2; ++t) {
            const int q = w * 2 + t;
            const int li = q * 512 + l * 8;
            const int row = li >> 5, kc = li & 31;
            const unsigned short* ga = A + (size_t)(bm + row) * K + k0 + kc;
            __builtin_amdgcn_global_load_lds(
                (const AS1 void*)ga, (AS3 void*)(As + q * 512), 16, 0, 0);
            const unsigned short* gb = Bt + (size_t)(bn + row) * K + k0 + kc;
            __builtin_amdgcn_global_load_lds(
                (const AS1 void*)gb, (AS3 void*)(Bs + q * 512), 16, 0, 0);
        }
        __syncthreads();

        short8 a[4], b[4];
#pragma unroll
        for (int i = 0; i < 4; ++i)
            a[i] = *(const short8*)(As + (wm + i * 16 + lrow) * 32 + lq * 8);
#pragma unroll
        for (int j = 0; j < 4; ++j)
            b[j] = *(const short8*)(Bs + (wn + j * 16 + lrow) * 32 + lq * 8);
#pragma unroll
        for (int i = 0; i < 4; ++i)
#pragma unroll
            for (int j = 0; j < 4; ++j)
                acc[i][j] = __builtin_amdgcn_mfma_f32_16x16x32_bf16(a[i], b[j], acc[i][j], 0, 0, 0);
        __syncthreads();
    }

#pragma unroll
    for (int i = 0; i < 4; ++i)
#pragma unroll
        for (int j = 0; j < 4; ++j) {
            const int col = bn + wn + j * 16 + lrow;
            const float bv = bias ? bias[col] : 0.f;
#pragma unroll
            for (int r = 0; r < 4; ++r) {
                const int row = bm + wm + i * 16 + lq * 4 + r;
                C[(size_t)row * N + col] = acc[i][j][r] + bv;
            }
        }
}

// ---------------------------------------------------------------------------
// Same GEMM but bf16 output, no bias (QKV projection)
// ---------------------------------------------------------------------------
__global__ __launch_bounds__(256) void gemm_bf16_bf(
    const unsigned short* __restrict__ A, const unsigned short* __restrict__ Bt,
    unsigned short* __restrict__ C, int M, int N, int K) {
    __shared__ short As[128 * 32];
    __shared__ short Bs[128 * 32];
    const int tid = threadIdx.x;
    const int w = tid >> 6, l = tid & 63;
    const int bm = blockIdx.y * 128, bn = blockIdx.x * 128;
    const int wm = (w >> 1) * 64, wn = (w & 1) * 64;
    const int lrow = l & 15, lq = l >> 4;

    f32x4 acc[4][4];
#pragma unroll
    for (int i = 0; i < 4; ++i)
#pragma unroll
        for (int j = 0; j < 4; ++j) acc[i][j] = (f32x4){0.f, 0.f, 0.f, 0.f};

    for (int k0 = 0; k0 < K; k0 += 32) {
#pragma unroll
        for (int t = 0; t < 2; ++t) {
            const int q = w * 2 + t;
            const int li = q * 512 + l * 8;
            const int row = li >> 5, kc = li & 31;
            const unsigned short* ga = A + (size_t)(bm + row) * K + k0 + kc;
            __builtin_amdgcn_global_load_lds(
                (const AS1 void*)ga, (AS3 void*)(As + q * 512), 16, 0, 0);
            const unsigned short* gb = Bt + (size_t)(bn + row) * K + k0 + kc;
            __builtin_amdgcn_global_load_lds(
                (const AS1 void*)gb, (AS3 void*)(Bs + q * 512), 16, 0, 0);
        }
        __syncthreads();

        short8 a[4], b[4];
#pragma unroll
        for (int i = 0; i < 4; ++i)
            a[i] = *(const short8*)(As + (wm + i * 16 + lrow) * 32 + lq * 8);
#pragma unroll
        for (int j = 0; j < 4; ++j)
            b[j] = *(const short8*)(Bs + (wn + j * 16 + lrow) * 32 + lq * 8);
#pragma unroll
        for (int i = 0; i < 4; ++i)
#pragma unroll
            for (int j = 0; j < 4; ++j)
                acc[i][j] = __builtin_amdgcn_mfma_f32_16x16x32_bf16(a[i], b[j], acc[i][j], 0, 0, 0);
        __syncthreads();
    }

#pragma unroll
    for (int i = 0; i < 4; ++i)
#pragma unroll
        for (int j = 0; j < 4; ++j) {
            const int col = bn + wn + j * 16 + lrow;
#pragma unroll
            for (int r = 0; r < 4; ++r) {
                const int row = bm + wm + i * 16 + lq * 4 + r;
                C[(size_t)row * N + col] = f2bf(acc[i][j][r]);
            }
        }
}

// ---------------------------------------------------------------------------
// STREAMING scores (R7): j-split x2, 4-deep register prefetch, no max-sub
// (scores bounded, fp32 exp can't overflow). attn gets UNNORMALIZED exp with
// PADDED plane stride; partial row-sums -> lsum2[jh][bh][i].
// ---------------------------------------------------------------------------
__global__ __launch_bounds__(256) void scores_stream(
    const unsigned short* __restrict__ qkvb, unsigned short* __restrict__ attnb,
    float* __restrict__ lsum2) {
    const int bh = blockIdx.z;
    const int h = bh & 15, b = bh >> 4;
    const int jh = blockIdx.y;                 // j half: 0 or 1
    const int w = threadIdx.x >> 6, l = threadIdx.x & 63;
    const int i0 = blockIdx.x * 64 + w * 16;   // wave-private 16-row i-tile
    const int lrow = l & 15, lq = l >> 4;

    const unsigned short* qb = qkvb + (size_t)(b * NN) * QKV3 + h * DH + lq * 8;
    const unsigned short* kb = qkvb + (size_t)(b * NN) * QKV3 + INNER + h * DH + lq * 8;

    const short8 qf0 = *(const short8*)(qb + (size_t)(i0 + lrow) * QKV3);
    const short8 qf1 = *(const short8*)(qb + (size_t)(i0 + lrow) * QKV3 + 32);

    const unsigned short* krow = kb + (size_t)(jh * 256 + lrow) * QKV3;
    unsigned short* orow = attnb + (size_t)bh * PSTR + (size_t)(i0 + lrow) * NN +
                           jh * 256 + lq * 4;

    short8 ka[4], kc[4];
#pragma unroll
    for (int p = 0; p < 4; ++p) {
        const unsigned short* kp = krow + (size_t)p * 16 * QKV3;
        ka[p] = *(const short8*)(kp);
        kc[p] = *(const short8*)(kp + 32);
    }

    float lacc = 0.f;
#pragma unroll
    for (int jt = 0; jt < 16; ++jt) {
        const int s = jt & 3;
        short8 kf0 = ka[s], kf1 = kc[s];
        if (jt < 12) {
            const unsigned short* kp = krow + (size_t)(jt + 4) * 16 * QKV3;
            ka[s] = *(const short8*)(kp);
            kc[s] = *(const short8*)(kp + 32);
        }
        f32x4 acc = (f32x4){0.f, 0.f, 0.f, 0.f};
        acc = __builtin_amdgcn_mfma_f32_16x16x32_bf16(kf0, qf0, acc, 0, 0, 0);
        acc = __builtin_amdgcn_mfma_f32_16x16x32_bf16(kf1, qf1, acc, 0, 0, 0);
        float e0 = __expf(acc[0] * 0.125f);
        float e1 = __expf(acc[1] * 0.125f);
        float e2 = __expf(acc[2] * 0.125f);
        float e3 = __expf(acc[3] * 0.125f);
        lacc += (e0 + e1) + (e2 + e3);
        ushort4 o;
        o.x = f2bf(e0); o.y = f2bf(e1); o.z = f2bf(e2); o.w = f2bf(e3);
        *(ushort4*)(orow + jt * 16) = o;
    }
    lacc += __shfl_xor(lacc, 16, 64);
    lacc += __shfl_xor(lacc, 32, 64);
    if (lq == 0)
        lsum2[(size_t)jh * BB * HH * NN + (size_t)bh * NN + i0 + lrow] = lacc;
}

// ---------------------------------------------------------------------------
// Re-attention + LN over heads, bf16 in/out (fp32 math), 4 j per thread.
// Inputs are UNNORMALIZED exp values; scale by 1/(l0+l1) on load.
// attn planes at PADDED stride PSTR (de-aliases the 16-plane gather).
// ---------------------------------------------------------------------------
__global__ void reattn_ln_bf(unsigned short* __restrict__ attnb,
                             const float* __restrict__ lsum2,
                             const float* __restrict__ rw,
                             const float* __restrict__ gamma,
                             const float* __restrict__ beta) {
    __shared__ float w[16][16];
    __shared__ float gs[16], bs[16];
    const int tid = threadIdx.x;
    ((float*)w)[tid] = rw[tid];
    if (tid < 16) { gs[tid] = gamma[tid]; bs[tid] = beta[tid]; }
    __syncthreads();

    const size_t idx = (size_t)blockIdx.x * 256 + tid;  // over B*N*N/4
    const int j4 = (int)(idx & 127);
    const int i = (int)((idx >> 7) & 511);
    const int b = (int)(idx >> 16);
    unsigned short* base = attnb + (size_t)(b * HH) * PSTR + (size_t)i * NN + j4 * 4;
    const float* l0 = lsum2 + (size_t)(b * HH) * NN + i;
    const float* l1 = l0 + (size_t)BB * HH * NN;

    float v[16][4];
#pragma unroll
    for (int h = 0; h < 16; ++h) {
        const float linv = 1.0f / (l0[h * NN] + l1[h * NN]);
        ushort4 u = *(const ushort4*)(base + (size_t)h * PSTR);
        v[h][0] = bf2f(u.x) * linv; v[h][1] = bf2f(u.y) * linv;
        v[h][2] = bf2f(u.z) * linv; v[h][3] = bf2f(u.w) * linv;
    }
    float o[16][4];
    float me[4] = {0.f, 0.f, 0.f, 0.f};
#pragma unroll
    for (int g = 0; g < 16; ++g) {
        float s0 = 0.f, s1 = 0.f, s2 = 0.f, s3 = 0.f;
#pragma unroll
        for (int h = 0; h < 16; ++h) {
            const float wg = w[h][g];
            s0 += v[h][0] * wg; s1 += v[h][1] * wg;
            s2 += v[h][2] * wg; s3 += v[h][3] * wg;
        }
        o[g][0] = s0; o[g][1] = s1; o[g][2] = s2; o[g][3] = s3;
        me[0] += s0; me[1] += s1; me[2] += s2; me[3] += s3;
    }
#pragma unroll
    for (int r = 0; r < 4; ++r) me[r] *= 0.0625f;
    float va[4] = {0.f, 0.f, 0.f, 0.f};
#pragma unroll
    for (int g = 0; g < 16; ++g)
#pragma unroll
        for (int r = 0; r < 4; ++r) {
            float d = o[g][r] - me[r];
            va[r] += d * d;
        }
    float ri[4];
#pragma unroll
    for (int r = 0; r < 4; ++r) ri[r] = rsqrtf(va[r] * 0.0625f + 1e-3f);
#pragma unroll
    for (int g = 0; g < 16; ++g) {
        ushort4 u;
        u.x = f2bf((o[g][0] - me[0]) * ri[0] * gs[g] + bs[g]);
        u.y = f2bf((o[g][1] - me[1]) * ri[1] * gs[g] + bs[g]);
        u.z = f2bf((o[g][2] - me[2]) * ri[2] * gs[g] + bs[g]);
        u.w = f2bf((o[g][3] - me[3]) * ri[3] * gs[g] + bs[g]);
        *(ushort4*)(base + (size_t)g * PSTR) = u;
    }
}

// ---------------------------------------------------------------------------
// V transpose: qkvb [b,j,2048+h*64+d] -> vT [bh, d, j] (bf16)
// ---------------------------------------------------------------------------
__global__ void transpose_v(const unsigned short* __restrict__ qkvb,
                            unsigned short* __restrict__ vT) {
    __shared__ unsigned short t[32][33];
    const int bh = blockIdx.z;
    const int h = bh & 15, b = bh >> 4;
    const int j0 = blockIdx.x * 32, d0 = blockIdx.y * 32;
    const int tx = threadIdx.x & 31, ty = threadIdx.x >> 5;
    const unsigned short* src = qkvb + (size_t)(b * NN) * QKV3 + 2 * INNER + h * DH;
#pragma unroll
    for (int k = 0; k < 4; ++k)
        t[ty + 8 * k][tx] = src[(size_t)(j0 + ty + 8 * k) * QKV3 + d0 + tx];
    __syncthreads();
    unsigned short* dst = vT + (size_t)bh * DH * NN;
#pragma unroll
    for (int k = 0; k < 4; ++k)
        dst[(size_t)(d0 + ty + 8 * k) * NN + j0 + tx] = t[tx][ty + 8 * k];
}

// ---------------------------------------------------------------------------
// PV MFMA: outh[b,i,h*64+d] = sum_j P[bh,i,j] V[bh,j,d], P bf16 (padded
// plane stride), vT bf16. Transposed-D: lane holds col i, rows d.
// ---------------------------------------------------------------------------
__global__ __launch_bounds__(256) void pv_mfma(
    const unsigned short* __restrict__ attnb, const unsigned short* __restrict__ vT,
    unsigned short* __restrict__ outhb) {
    const int bh = blockIdx.y;
    const int h = bh & 15, b = bh >> 4;
    const int i0 = blockIdx.x * 128;
    __shared__ short Ps[128 * 64];
    __shared__ short Vs[64 * 64];
    const int tid = threadIdx.x;
    const int w = tid >> 6, l = tid & 63;
    const int lrow = l & 15, lq = l >> 4;
    const int lr8 = l >> 3;
    const int swd = ((l & 7) ^ (lr8 & 7)) * 8;

    f32x4 acc[2][4];
#pragma unroll
    for (int ic = 0; ic < 2; ++ic)
#pragma unroll
        for (int dt = 0; dt < 4; ++dt) acc[ic][dt] = (f32x4){0.f, 0.f, 0.f, 0.f};

    const unsigned short* pb = attnb + (size_t)bh * PSTR + (size_t)i0 * NN;
    const unsigned short* vb = vT + (size_t)bh * DH * NN;

    for (int j0 = 0; j0 < NN; j0 += 64) {
#pragma unroll
        for (int t = 0; t < 4; ++t) {
            int c = w * 4 + t;
            int r = c * 8 + lr8;
            __builtin_amdgcn_global_load_lds(
                (const AS1 void*)(pb + (size_t)r * NN + j0 + swd),
                (AS3 void*)(Ps + c * 512), 16, 0, 0);
        }
#pragma unroll
        for (int t = 0; t < 2; ++t) {
            int c = w * 2 + t;
            int d = c * 8 + lr8;
            __builtin_amdgcn_global_load_lds(
                (const AS1 void*)(vb + (size_t)d * NN + j0 + swd),
                (AS3 void*)(Vs + c * 512), 16, 0, 0);
        }
        __syncthreads();

#pragma unroll
        for (int kh = 0; kh < 2; ++kh) {
            short8 vf[4];
#pragma unroll
            for (int dt = 0; dt < 4; ++dt)
                vf[dt] = *(const short8*)(Vs + (dt * 16 + lrow) * 64 + (((kh * 4 + lq) ^ (lrow & 7)) * 8));
#pragma unroll
            for (int ic = 0; ic < 2; ++ic) {
                short8 pf = *(const short8*)(Ps + (w * 32 + ic * 16 + lrow) * 64 + (((kh * 4 + lq) ^ (lrow & 7)) * 8));
#pragma unroll
                for (int dt = 0; dt < 4; ++dt)
                    acc[ic][dt] = __builtin_amdgcn_mfma_f32_16x16x32_bf16(vf[dt], pf, acc[ic][dt], 0, 0, 0);
            }
        }
        __syncthreads();
    }

#pragma unroll
    for (int ic = 0; ic < 2; ++ic) {
        unsigned short* orow = outhb +
            ((size_t)(b * NN + i0 + w * 32 + ic * 16 + lrow)) * INNER + h * DH + lq * 4;
#pragma unroll
        for (int dt = 0; dt < 4; ++dt) {
            ushort4 o;
            o.x = f2bf(acc[ic][dt][0]); o.y = f2bf(acc[ic][dt][1]);
            o.z = f2bf(acc[ic][dt][2]); o.w = f2bf(acc[ic][dt][3]);
            *(ushort4*)(orow + dt * 16) = o;
        }
    }
}

// ---------------------------------------------------------------------------
extern "C" void kernel_launch(void* const* d_in, const int* in_sizes, int n_in,
                              void* d_out, int out_size, void* d_ws, size_t ws_size,
                              hipStream_t stream) {
    const float* x        = (const float*)d_in[0];
    const float* w_qkv    = (const float*)d_in[1];
    const float* reattn_w = (const float*)d_in[2];
    const float* ln_gamma = (const float*)d_in[3];
    const float* ln_beta  = (const float*)d_in[4];
    const float* w_out    = (const float*)d_in[5];
    const float* b_out    = (const float*)d_in[6];
    float* out = (float*)d_out;

    unsigned short* qkvb  = (unsigned short*)d_ws;                 // 12.58M
    unsigned short* attnb = qkvb + (size_t)BB * NN * QKV3;         // 128 * PSTR
    unsigned short* vTb   = attnb + (size_t)BB * HH * PSTR;        // 4.19M
    unsigned short* outhb = vTb + (size_t)BB * HH * DH * NN;       // 4.19M
    unsigned short* xb    = outhb + (size_t)BB * NN * INNER;       // 4.19M
    unsigned short* wqkvT = xb + (size_t)BB * NN * DD;             // 3.15M
    unsigned short* woutT = wqkvT + (size_t)DD * QKV3;             // 1.05M
    float*          lsum2 = (float*)(woutT + (size_t)INNER * INNER);  // 2*B*H*N f32

    dim3 blk(256);

    conv_bf16<<<dim3((BB * NN * DD) / 1024), blk, 0, stream>>>(x, xb);
    convT_bf16<<<dim3(QKV3 / 32, DD / 32), blk, 0, stream>>>(w_qkv, wqkvT, DD, QKV3);
    convT_bf16<<<dim3(INNER / 32, INNER / 32), blk, 0, stream>>>(w_out, woutT, INNER, INNER);

    // QKV projection -> bf16
    gemm_bf16_bf<<<dim3(QKV3 / 128, (BB * NN) / 128), blk, 0, stream>>>(
        xb, wqkvT, qkvb, BB * NN, QKV3, DD);

    // streaming scores: unnormalized exp -> attn bf16 (padded planes)
    scores_stream<<<dim3(NN / 64, 2, BB * HH), blk, 0, stream>>>(qkvb, attnb, lsum2);

    // re-attention + LN (normalizes by 1/(l0+l1) on load, in-place bf16)
    reattn_ln_bf<<<dim3((BB * NN * NN) / 1024), blk, 0, stream>>>(
        attnb, lsum2, reattn_w, ln_gamma, ln_beta);

    // V transpose -> [bh][d][j]
    transpose_v<<<dim3(NN / 32, DH / 32, BB * HH), blk, 0, stream>>>(qkvb, vTb);

    // P @ V -> outh bf16
    pv_mfma<<<dim3(NN / 128, BB * HH), blk, 0, stream>>>(attnb, vTb, outhb);

    // output projection + bias (fp32 out)
    gemm_bf16<<<dim3(INNER / 128, (BB * NN) / 128), blk, 0, stream>>>(
        outhb, woutT, out, b_out, BB * NN, INNER, INNER);
}

// Round 3
// 244.084 us; speedup vs baseline: 1.0048x; 1.0048x over previous
//
#include <hip/hip_runtime.h>
#include <math.h>

#define BB 8
#define NN 512
#define DD 1024
#define HH 16
#define DH 64
#define INNER 1024
#define QKV3 3072
// attn head-plane stride in shorts: N*N + 64 (128B pad) breaks the exact
// 512KB power-of-2 stride that aliases all 16 head planes onto the same
// L2-set/HBM-channel group in reattn_ln_bf's 16-plane gather.
#define PSTR (NN * NN + 64)

typedef __attribute__((ext_vector_type(8))) short short8;
typedef __attribute__((ext_vector_type(4))) float f32x4;

#define AS1 __attribute__((address_space(1)))
#define AS3 __attribute__((address_space(3)))

__device__ __forceinline__ float4 ld4(const float* p) { return *(const float4*)p; }

__device__ __forceinline__ unsigned short f2bf(float f) {
    unsigned u = __float_as_uint(f);
    return (unsigned short)((u + 0x7fffu + ((u >> 16) & 1u)) >> 16);
}
__device__ __forceinline__ float bf2f(unsigned short u) {
    return __uint_as_float(((unsigned)u) << 16);
}

// ---------------------------------------------------------------------------
// fp32 -> bf16 elementwise convert (4 els/thread)
// ---------------------------------------------------------------------------
__global__ void conv_bf16(const float* __restrict__ in, unsigned short* __restrict__ out) {
    size_t i = ((size_t)blockIdx.x * 256 + threadIdx.x) * 4;
    float4 v = ld4(in + i);
    ushort4 o;
    o.x = f2bf(v.x); o.y = f2bf(v.y); o.z = f2bf(v.z); o.w = f2bf(v.w);
    *(ushort4*)(out + i) = o;
}

// ---------------------------------------------------------------------------
// fp32 [K][N] -> bf16 [N][K] transpose-convert, 32x32 LDS tiles
// ---------------------------------------------------------------------------
__global__ void convT_bf16(const float* __restrict__ in, unsigned short* __restrict__ out,
                           int K, int N) {
    __shared__ float t[32][33];
    const int n0 = blockIdx.x * 32, k0 = blockIdx.y * 32;
    const int tx = threadIdx.x & 31, ty = threadIdx.x >> 5;  // 32 x 8
#pragma unroll
    for (int l = 0; l < 4; ++l)
        t[ty + 8 * l][tx] = in[(size_t)(k0 + ty + 8 * l) * N + n0 + tx];
    __syncthreads();
#pragma unroll
    for (int l = 0; l < 4; ++l)
        out[(size_t)(n0 + ty + 8 * l) * K + k0 + tx] = f2bf(t[tx][ty + 8 * l]);
}

// ---------------------------------------------------------------------------
// bf16 MFMA GEMM, fp32 out (+bias): C[M,N] = A[M,K] * Bt[N,K]^T   (128x128)
// ---------------------------------------------------------------------------
__global__ __launch_bounds__(256) void gemm_bf16(
    const unsigned short* __restrict__ A, const unsigned short* __restrict__ Bt,
    float* __restrict__ C, const float* __restrict__ bias, int M, int N, int K) {
    __shared__ short As[128 * 32];
    __shared__ short Bs[128 * 32];
    const int tid = threadIdx.x;
    const int w = tid >> 6, l = tid & 63;
    const int bm = blockIdx.y * 128, bn = blockIdx.x * 128;
    const int wm = (w >> 1) * 64, wn = (w & 1) * 64;
    const int lrow = l & 15, lq = l >> 4;

    f32x4 acc[4][4];
#pragma unroll
    for (int i = 0; i < 4; ++i)
#pragma unroll
        for (int j = 0; j < 4; ++j) acc[i][j] = (f32x4){0.f, 0.f, 0.f, 0.f};

    for (int k0 = 0; k0 < K; k0 += 32) {
#pragma unroll
        for (int t = 0; t < 2; ++t) {
            const int q = w * 2 + t;
            const int li = q * 512 + l * 8;
            const int row = li >> 5, kc = li & 31;
            const unsigned short* ga = A + (size_t)(bm + row) * K + k0 + kc;
            __builtin_amdgcn_global_load_lds(
                (const AS1 void*)ga, (AS3 void*)(As + q * 512), 16, 0, 0);
            const unsigned short* gb = Bt + (size_t)(bn + row) * K + k0 + kc;
            __builtin_amdgcn_global_load_lds(
                (const AS1 void*)gb, (AS3 void*)(Bs + q * 512), 16, 0, 0);
        }
        __syncthreads();

        short8 a[4], b[4];
#pragma unroll
        for (int i = 0; i < 4; ++i)
            a[i] = *(const short8*)(As + (wm + i * 16 + lrow) * 32 + lq * 8);
#pragma unroll
        for (int j = 0; j < 4; ++j)
            b[j] = *(const short8*)(Bs + (wn + j * 16 + lrow) * 32 + lq * 8);
#pragma unroll
        for (int i = 0; i < 4; ++i)
#pragma unroll
            for (int j = 0; j < 4; ++j)
                acc[i][j] = __builtin_amdgcn_mfma_f32_16x16x32_bf16(a[i], b[j], acc[i][j], 0, 0, 0);
        __syncthreads();
    }

#pragma unroll
    for (int i = 0; i < 4; ++i)
#pragma unroll
        for (int j = 0; j < 4; ++j) {
            const int col = bn + wn + j * 16 + lrow;
            const float bv = bias ? bias[col] : 0.f;
#pragma unroll
            for (int r = 0; r < 4; ++r) {
                const int row = bm + wm + i * 16 + lq * 4 + r;
                C[(size_t)row * N + col] = acc[i][j][r] + bv;
            }
        }
}

// ---------------------------------------------------------------------------
// 256x256-tile bf16 GEMM, bf16 out (QKV projection).
// 8 waves (2Mx4N), BK=32, phase-pipelined K-loop with counted vmcnt (T3+T4),
// st_16x32-style XOR swizzle (pre-swizzled global source + swizzled ds_read,
// same involution both sides), raw s_barrier (no vmcnt(0) drain in main loop),
// setprio around MFMA cluster (T5).
//
// LDS: 2 slots x (A 256x32 + B 256x32) bf16 = 64KB static.
// Region layout (shorts): slot*16384 + {A:0,B:8192} + half*4096 + rg*512,
// subtile = 16 rows x 32 cols, element (r,c) at phys = (r*32+c) ^ ((r&8)<<1).
//
// Staging cadence for tile t (slot s=t&1), one half-tile per phase:
//   p0: A-half0(t+1)->slot s^1   p1: A-half1(t+1)->slot s^1
//   p2: B-half0(t+2)->slot s     p3: B-half1(t+2)->slot s
// Per-wave vmcnt FIFO at p3: [B01(t+1)(2), A01(t+1)(2), B01(t+2)(2)] = 6
// outstanding -> s_waitcnt vmcnt(2) guarantees tile t+1 fully landed.
// B(slot s) is read only in p0 (all waves lgkmcnt(0)+barrier before p2's
// overwrite); A(slot s^1) was last read in tile t-1. No drain until t==NT-2.
// ---------------------------------------------------------------------------
__device__ __forceinline__ void stage_st(const unsigned short* __restrict__ G, int K,
                                         int row0, int kt, short* dst_half,
                                         int w, int l) {
    // wave w fills subtile rg=w (16 rows x 32 cols, 1KB). global_load_lds dest
    // is wave-uniform base + lane*16B (linear); source is per-lane and carries
    // the inverse swizzle: lane l -> row (l>>2), colshorts ((l&3)*8)^((l&32)?16:0).
    const int grow = row0 + w * 16 + (l >> 2);
    const int gcol = kt * 32 + (((l & 3) * 8) ^ ((l & 32) ? 16 : 0));
    __builtin_amdgcn_global_load_lds(
        (const AS1 void*)(G + (size_t)grow * K + gcol),
        (AS3 void*)(dst_half + w * 512), 16, 0, 0);
}

__global__ __launch_bounds__(512, 2) void gemm256_bf(
    const unsigned short* __restrict__ A, const unsigned short* __restrict__ Bt,
    unsigned short* __restrict__ C, int M, int N, int K) {
    __shared__ __align__(16) short lds_[2 * 16384];
    const int tid = threadIdx.x;
    const int w = tid >> 6, l = tid & 63;
    const int wm = w >> 2, wn = w & 3;          // 2 x 4 wave grid
    const int lrow = l & 15, lq = l >> 4;
    const int bm = blockIdx.y * 256, bn = blockIdx.x * 256;
    const int NT = K >> 5;                       // K-tiles of 32

    // swizzled ds_read offset within a subtile (shorts)
    const int aoff = lrow * 32 + ((lq * 8) ^ ((lrow & 8) ? 16 : 0));
    const int bsub = (wn & 1) * 4;              // B rg base for this wave

    f32x4 acc[8][4];
#pragma unroll
    for (int i = 0; i < 8; ++i)
#pragma unroll
        for (int j = 0; j < 4; ++j) acc[i][j] = (f32x4){0.f, 0.f, 0.f, 0.f};

    // ---- prologue: tile0 A+B, tile1 B; wait first 4 groups ----
    stage_st(A,  K, bm,       0, lds_ + 0,                    w, l);
    stage_st(A,  K, bm + 128, 0, lds_ + 4096,                 w, l);
    stage_st(Bt, K, bn,       0, lds_ + 8192,                 w, l);
    stage_st(Bt, K, bn + 128, 0, lds_ + 8192 + 4096,          w, l);
    stage_st(Bt, K, bn,       1, lds_ + 16384 + 8192,         w, l);
    stage_st(Bt, K, bn + 128, 1, lds_ + 16384 + 8192 + 4096,  w, l);
    asm volatile("s_waitcnt vmcnt(2)" ::: "memory");
    __builtin_amdgcn_s_barrier();

    for (int t = 0; t < NT; ++t) {
        const int s = t & 1;
        const short* Ah = lds_ + s * 16384 + wm * 4096;
        const short* Bh = lds_ + s * 16384 + 8192 + (wn >> 1) * 4096;
        short8 bfr[4];
#pragma unroll
        for (int p = 0; p < 4; ++p) {
            // ds_read this phase's A frag pair (and all B frags at p0)
            short8 a0 = *(const short8*)(Ah + (2 * p) * 512 + aoff);
            short8 a1 = *(const short8*)(Ah + (2 * p + 1) * 512 + aoff);
            if (p == 0) {
#pragma unroll
                for (int fc = 0; fc < 4; ++fc)
                    bfr[fc] = *(const short8*)(Bh + (bsub + fc) * 512 + aoff);
            }
            // stage duty (one half-tile per phase)
            if (p == 0 && t + 1 < NT)
                stage_st(A,  K, bm,       t + 1, lds_ + (s ^ 1) * 16384,               w, l);
            if (p == 1 && t + 1 < NT)
                stage_st(A,  K, bm + 128, t + 1, lds_ + (s ^ 1) * 16384 + 4096,        w, l);
            if (p == 2 && t + 2 < NT)
                stage_st(Bt, K, bn,       t + 2, lds_ + s * 16384 + 8192,              w, l);
            if (p == 3 && t + 2 < NT)
                stage_st(Bt, K, bn + 128, t + 2, lds_ + s * 16384 + 8192 + 4096,       w, l);

            __builtin_amdgcn_s_barrier();
            asm volatile("s_waitcnt lgkmcnt(0)" ::: "memory");
            __builtin_amdgcn_sched_barrier(0);   // rule #18: pin MFMA below the wait

            __builtin_amdgcn_s_setprio(1);
#pragma unroll
            for (int fc = 0; fc < 4; ++fc) {
                acc[2 * p][fc] =
                    __builtin_amdgcn_mfma_f32_16x16x32_bf16(a0, bfr[fc], acc[2 * p][fc], 0, 0, 0);
                acc[2 * p + 1][fc] =
                    __builtin_amdgcn_mfma_f32_16x16x32_bf16(a1, bfr[fc], acc[2 * p + 1][fc], 0, 0, 0);
            }
            __builtin_amdgcn_s_setprio(0);

            if (p == 3) {
                if (t == NT - 2)
                    asm volatile("s_waitcnt vmcnt(0)" ::: "memory");
                else if (t < NT - 2)
                    asm volatile("s_waitcnt vmcnt(2)" ::: "memory");
            }
            __builtin_amdgcn_s_barrier();
        }
    }

    // ---- epilogue: bf16 C ----
#pragma unroll
    for (int fr = 0; fr < 8; ++fr)
#pragma unroll
        for (int fc = 0; fc < 4; ++fc) {
            const int col = bn + wn * 64 + fc * 16 + lrow;
#pragma unroll
            for (int r = 0; r < 4; ++r) {
                const int row = bm + wm * 128 + fr * 16 + lq * 4 + r;
                C[(size_t)row * N + col] = f2bf(acc[fr][fc][r]);
            }
        }
}

// ---------------------------------------------------------------------------
// STREAMING scores (R7): j-split x2, 4-deep register prefetch, no max-sub
// (scores bounded, fp32 exp can't overflow). attn gets UNNORMALIZED exp with
// PADDED plane stride; partial row-sums -> lsum2[jh][bh][i].
// ---------------------------------------------------------------------------
__global__ __launch_bounds__(256) void scores_stream(
    const unsigned short* __restrict__ qkvb, unsigned short* __restrict__ attnb,
    float* __restrict__ lsum2) {
    const int bh = blockIdx.z;
    const int h = bh & 15, b = bh >> 4;
    const int jh = blockIdx.y;                 // j half: 0 or 1
    const int w = threadIdx.x >> 6, l = threadIdx.x & 63;
    const int i0 = blockIdx.x * 64 + w * 16;   // wave-private 16-row i-tile
    const int lrow = l & 15, lq = l >> 4;

    const unsigned short* qb = qkvb + (size_t)(b * NN) * QKV3 + h * DH + lq * 8;
    const unsigned short* kb = qkvb + (size_t)(b * NN) * QKV3 + INNER + h * DH + lq * 8;

    const short8 qf0 = *(const short8*)(qb + (size_t)(i0 + lrow) * QKV3);
    const short8 qf1 = *(const short8*)(qb + (size_t)(i0 + lrow) * QKV3 + 32);

    const unsigned short* krow = kb + (size_t)(jh * 256 + lrow) * QKV3;
    unsigned short* orow = attnb + (size_t)bh * PSTR + (size_t)(i0 + lrow) * NN +
                           jh * 256 + lq * 4;

    short8 ka[4], kc[4];
#pragma unroll
    for (int p = 0; p < 4; ++p) {
        const unsigned short* kp = krow + (size_t)p * 16 * QKV3;
        ka[p] = *(const short8*)(kp);
        kc[p] = *(const short8*)(kp + 32);
    }

    float lacc = 0.f;
#pragma unroll
    for (int jt = 0; jt < 16; ++jt) {
        const int s = jt & 3;
        short8 kf0 = ka[s], kf1 = kc[s];
        if (jt < 12) {
            const unsigned short* kp = krow + (size_t)(jt + 4) * 16 * QKV3;
            ka[s] = *(const short8*)(kp);
            kc[s] = *(const short8*)(kp + 32);
        }
        f32x4 acc = (f32x4){0.f, 0.f, 0.f, 0.f};
        acc = __builtin_amdgcn_mfma_f32_16x16x32_bf16(kf0, qf0, acc, 0, 0, 0);
        acc = __builtin_amdgcn_mfma_f32_16x16x32_bf16(kf1, qf1, acc, 0, 0, 0);
        float e0 = __expf(acc[0] * 0.125f);
        float e1 = __expf(acc[1] * 0.125f);
        float e2 = __expf(acc[2] * 0.125f);
        float e3 = __expf(acc[3] * 0.125f);
        lacc += (e0 + e1) + (e2 + e3);
        ushort4 o;
        o.x = f2bf(e0); o.y = f2bf(e1); o.z = f2bf(e2); o.w = f2bf(e3);
        *(ushort4*)(orow + jt * 16) = o;
    }
    lacc += __shfl_xor(lacc, 16, 64);
    lacc += __shfl_xor(lacc, 32, 64);
    if (lq == 0)
        lsum2[(size_t)jh * BB * HH * NN + (size_t)bh * NN + i0 + lrow] = lacc;
}

// ---------------------------------------------------------------------------
// Re-attention + LN over heads, bf16 in/out (fp32 math), 4 j per thread.
// Inputs are UNNORMALIZED exp values; scale by 1/(l0+l1) on load.
// attn planes at PADDED stride PSTR (de-aliases the 16-plane gather).
// ---------------------------------------------------------------------------
__global__ void reattn_ln_bf(unsigned short* __restrict__ attnb,
                             const float* __restrict__ lsum2,
                             const float* __restrict__ rw,
                             const float* __restrict__ gamma,
                             const float* __restrict__ beta) {
    __shared__ float w[16][16];
    __shared__ float gs[16], bs[16];
    const int tid = threadIdx.x;
    ((float*)w)[tid] = rw[tid];
    if (tid < 16) { gs[tid] = gamma[tid]; bs[tid] = beta[tid]; }
    __syncthreads();

    const size_t idx = (size_t)blockIdx.x * 256 + tid;  // over B*N*N/4
    const int j4 = (int)(idx & 127);
    const int i = (int)((idx >> 7) & 511);
    const int b = (int)(idx >> 16);
    unsigned short* base = attnb + (size_t)(b * HH) * PSTR + (size_t)i * NN + j4 * 4;
    const float* l0 = lsum2 + (size_t)(b * HH) * NN + i;
    const float* l1 = l0 + (size_t)BB * HH * NN;

    float v[16][4];
#pragma unroll
    for (int h = 0; h < 16; ++h) {
        const float linv = 1.0f / (l0[h * NN] + l1[h * NN]);
        ushort4 u = *(const ushort4*)(base + (size_t)h * PSTR);
        v[h][0] = bf2f(u.x) * linv; v[h][1] = bf2f(u.y) * linv;
        v[h][2] = bf2f(u.z) * linv; v[h][3] = bf2f(u.w) * linv;
    }
    float o[16][4];
    float me[4] = {0.f, 0.f, 0.f, 0.f};
#pragma unroll
    for (int g = 0; g < 16; ++g) {
        float s0 = 0.f, s1 = 0.f, s2 = 0.f, s3 = 0.f;
#pragma unroll
        for (int h = 0; h < 16; ++h) {
            const float wg = w[h][g];
            s0 += v[h][0] * wg; s1 += v[h][1] * wg;
            s2 += v[h][2] * wg; s3 += v[h][3] * wg;
        }
        o[g][0] = s0; o[g][1] = s1; o[g][2] = s2; o[g][3] = s3;
        me[0] += s0; me[1] += s1; me[2] += s2; me[3] += s3;
    }
#pragma unroll
    for (int r = 0; r < 4; ++r) me[r] *= 0.0625f;
    float va[4] = {0.f, 0.f, 0.f, 0.f};
#pragma unroll
    for (int g = 0; g < 16; ++g)
#pragma unroll
        for (int r = 0; r < 4; ++r) {
            float d = o[g][r] - me[r];
            va[r] += d * d;
        }
    float ri[4];
#pragma unroll
    for (int r = 0; r < 4; ++r) ri[r] = rsqrtf(va[r] * 0.0625f + 1e-3f);
#pragma unroll
    for (int g = 0; g < 16; ++g) {
        ushort4 u;
        u.x = f2bf((o[g][0] - me[0]) * ri[0] * gs[g] + bs[g]);
        u.y = f2bf((o[g][1] - me[1]) * ri[1] * gs[g] + bs[g]);
        u.z = f2bf((o[g][2] - me[2]) * ri[2] * gs[g] + bs[g]);
        u.w = f2bf((o[g][3] - me[3]) * ri[3] * gs[g] + bs[g]);
        *(ushort4*)(base + (size_t)g * PSTR) = u;
    }
}

// ---------------------------------------------------------------------------
// V transpose: qkvb [b,j,2048+h*64+d] -> vT [bh, d, j] (bf16)
// ---------------------------------------------------------------------------
__global__ void transpose_v(const unsigned short* __restrict__ qkvb,
                            unsigned short* __restrict__ vT) {
    __shared__ unsigned short t[32][33];
    const int bh = blockIdx.z;
    const int h = bh & 15, b = bh >> 4;
    const int j0 = blockIdx.x * 32, d0 = blockIdx.y * 32;
    const int tx = threadIdx.x & 31, ty = threadIdx.x >> 5;
    const unsigned short* src = qkvb + (size_t)(b * NN) * QKV3 + 2 * INNER + h * DH;
#pragma unroll
    for (int k = 0; k < 4; ++k)
        t[ty + 8 * k][tx] = src[(size_t)(j0 + ty + 8 * k) * QKV3 + d0 + tx];
    __syncthreads();
    unsigned short* dst = vT + (size_t)bh * DH * NN;
#pragma unroll
    for (int k = 0; k < 4; ++k)
        dst[(size_t)(d0 + ty + 8 * k) * NN + j0 + tx] = t[tx][ty + 8 * k];
}

// ---------------------------------------------------------------------------
// PV MFMA: outh[b,i,h*64+d] = sum_j P[bh,i,j] V[bh,j,d], P bf16 (padded
// plane stride), vT bf16. Transposed-D: lane holds col i, rows d.
// ---------------------------------------------------------------------------
__global__ __launch_bounds__(256) void pv_mfma(
    const unsigned short* __restrict__ attnb, const unsigned short* __restrict__ vT,
    unsigned short* __restrict__ outhb) {
    const int bh = blockIdx.y;
    const int h = bh & 15, b = bh >> 4;
    const int i0 = blockIdx.x * 128;
    __shared__ short Ps[128 * 64];
    __shared__ short Vs[64 * 64];
    const int tid = threadIdx.x;
    const int w = tid >> 6, l = tid & 63;
    const int lrow = l & 15, lq = l >> 4;
    const int lr8 = l >> 3;
    const int swd = ((l & 7) ^ (lr8 & 7)) * 8;

    f32x4 acc[2][4];
#pragma unroll
    for (int ic = 0; ic < 2; ++ic)
#pragma unroll
        for (int dt = 0; dt < 4; ++dt) acc[ic][dt] = (f32x4){0.f, 0.f, 0.f, 0.f};

    const unsigned short* pb = attnb + (size_t)bh * PSTR + (size_t)i0 * NN;
    const unsigned short* vb = vT + (size_t)bh * DH * NN;

    for (int j0 = 0; j0 < NN; j0 += 64) {
#pragma unroll
        for (int t = 0; t < 4; ++t) {
            int c = w * 4 + t;
            int r = c * 8 + lr8;
            __builtin_amdgcn_global_load_lds(
                (const AS1 void*)(pb + (size_t)r * NN + j0 + swd),
                (AS3 void*)(Ps + c * 512), 16, 0, 0);
        }
#pragma unroll
        for (int t = 0; t < 2; ++t) {
            int c = w * 2 + t;
            int d = c * 8 + lr8;
            __builtin_amdgcn_global_load_lds(
                (const AS1 void*)(vb + (size_t)d * NN + j0 + swd),
                (AS3 void*)(Vs + c * 512), 16, 0, 0);
        }
        __syncthreads();

#pragma unroll
        for (int kh = 0; kh < 2; ++kh) {
            short8 vf[4];
#pragma unroll
            for (int dt = 0; dt < 4; ++dt)
                vf[dt] = *(const short8*)(Vs + (dt * 16 + lrow) * 64 + (((kh * 4 + lq) ^ (lrow & 7)) * 8));
#pragma unroll
            for (int ic = 0; ic < 2; ++ic) {
                short8 pf = *(const short8*)(Ps + (w * 32 + ic * 16 + lrow) * 64 + (((kh * 4 + lq) ^ (lrow & 7)) * 8));
#pragma unroll
                for (int dt = 0; dt < 4; ++dt)
                    acc[ic][dt] = __builtin_amdgcn_mfma_f32_16x16x32_bf16(vf[dt], pf, acc[ic][dt], 0, 0, 0);
            }
        }
        __syncthreads();
    }

#pragma unroll
    for (int ic = 0; ic < 2; ++ic) {
        unsigned short* orow = outhb +
            ((size_t)(b * NN + i0 + w * 32 + ic * 16 + lrow)) * INNER + h * DH + lq * 4;
#pragma unroll
        for (int dt = 0; dt < 4; ++dt) {
            ushort4 o;
            o.x = f2bf(acc[ic][dt][0]); o.y = f2bf(acc[ic][dt][1]);
            o.z = f2bf(acc[ic][dt][2]); o.w = f2bf(acc[ic][dt][3]);
            *(ushort4*)(orow + dt * 16) = o;
        }
    }
}

// ---------------------------------------------------------------------------
extern "C" void kernel_launch(void* const* d_in, const int* in_sizes, int n_in,
                              void* d_out, int out_size, void* d_ws, size_t ws_size,
                              hipStream_t stream) {
    const float* x        = (const float*)d_in[0];
    const float* w_qkv    = (const float*)d_in[1];
    const float* reattn_w = (const float*)d_in[2];
    const float* ln_gamma = (const float*)d_in[3];
    const float* ln_beta  = (const float*)d_in[4];
    const float* w_out    = (const float*)d_in[5];
    const float* b_out    = (const float*)d_in[6];
    float* out = (float*)d_out;

    unsigned short* qkvb  = (unsigned short*)d_ws;                 // 12.58M
    unsigned short* attnb = qkvb + (size_t)BB * NN * QKV3;         // 128 * PSTR
    unsigned short* vTb   = attnb + (size_t)BB * HH * PSTR;        // 4.19M
    unsigned short* outhb = vTb + (size_t)BB * HH * DH * NN;       // 4.19M
    unsigned short* xb    = outhb + (size_t)BB * NN * INNER;       // 4.19M
    unsigned short* wqkvT = xb + (size_t)BB * NN * DD;             // 3.15M
    unsigned short* woutT = wqkvT + (size_t)DD * QKV3;             // 1.05M
    float*          lsum2 = (float*)(woutT + (size_t)INNER * INNER);  // 2*B*H*N f32

    dim3 blk(256);

    conv_bf16<<<dim3((BB * NN * DD) / 1024), blk, 0, stream>>>(x, xb);
    convT_bf16<<<dim3(QKV3 / 32, DD / 32), blk, 0, stream>>>(w_qkv, wqkvT, DD, QKV3);
    convT_bf16<<<dim3(INNER / 32, INNER / 32), blk, 0, stream>>>(w_out, woutT, INNER, INNER);

    // QKV projection -> bf16 (256^2-tile phase-pipelined GEMM, 512 threads)
    gemm256_bf<<<dim3(QKV3 / 256, (BB * NN) / 256), dim3(512), 0, stream>>>(
        xb, wqkvT, qkvb, BB * NN, QKV3, DD);

    // streaming scores: unnormalized exp -> attn bf16 (padded planes)
    scores_stream<<<dim3(NN / 64, 2, BB * HH), blk, 0, stream>>>(qkvb, attnb, lsum2);

    // re-attention + LN (normalizes by 1/(l0+l1) on load, in-place bf16)
    reattn_ln_bf<<<dim3((BB * NN * NN) / 1024), blk, 0, stream>>>(
        attnb, lsum2, reattn_w, ln_gamma, ln_beta);

    // V transpose -> [bh][d][j]
    transpose_v<<<dim3(NN / 32, DH / 32, BB * HH), blk, 0, stream>>>(qkvb, vTb);

    // P @ V -> outh bf16
    pv_mfma<<<dim3(NN / 128, BB * HH), blk, 0, stream>>>(attnb, vTb, outhb);

    // output projection + bias (fp32 out)
    gemm_bf16<<<dim3(INNER / 128, (BB * NN) / 128), blk, 0, stream>>>(
        outhb, woutT, out, b_out, BB * NN, INNER, INNER);
}

// Round 4
// 238.390 us; speedup vs baseline: 1.0288x; 1.0239x over previous
//
#include <hip/hip_runtime.h>
#include <math.h>

#define BB 8
#define NN 512
#define DD 1024
#define HH 16
#define DH 64
#define INNER 1024
#define QKV3 3072
// attn head-plane stride in shorts: N*N + 64 (128B pad) breaks the exact
// 512KB power-of-2 stride that aliases all 16 head planes onto the same
// L2-set/HBM-channel group in reattn_ln_bf's 16-plane gather.
#define PSTR (NN * NN + 64)

typedef __attribute__((ext_vector_type(8))) short short8;
typedef __attribute__((ext_vector_type(4))) float f32x4;

#define AS1 __attribute__((address_space(1)))
#define AS3 __attribute__((address_space(3)))

__device__ __forceinline__ float4 ld4(const float* p) { return *(const float4*)p; }

__device__ __forceinline__ unsigned short f2bf(float f) {
    unsigned u = __float_as_uint(f);
    return (unsigned short)((u + 0x7fffu + ((u >> 16) & 1u)) >> 16);
}
__device__ __forceinline__ float bf2f(unsigned short u) {
    return __uint_as_float(((unsigned)u) << 16);
}

// ---------------------------------------------------------------------------
// fp32 -> bf16 elementwise convert (4 els/thread)
// ---------------------------------------------------------------------------
__global__ void conv_bf16(const float* __restrict__ in, unsigned short* __restrict__ out) {
    size_t i = ((size_t)blockIdx.x * 256 + threadIdx.x) * 4;
    float4 v = ld4(in + i);
    ushort4 o;
    o.x = f2bf(v.x); o.y = f2bf(v.y); o.z = f2bf(v.z); o.w = f2bf(v.w);
    *(ushort4*)(out + i) = o;
}

// ---------------------------------------------------------------------------
// fp32 [K][N] -> bf16 [N][K] transpose-convert, 32x32 LDS tiles
// ---------------------------------------------------------------------------
__global__ void convT_bf16(const float* __restrict__ in, unsigned short* __restrict__ out,
                           int K, int N) {
    __shared__ float t[32][33];
    const int n0 = blockIdx.x * 32, k0 = blockIdx.y * 32;
    const int tx = threadIdx.x & 31, ty = threadIdx.x >> 5;  // 32 x 8
#pragma unroll
    for (int l = 0; l < 4; ++l)
        t[ty + 8 * l][tx] = in[(size_t)(k0 + ty + 8 * l) * N + n0 + tx];
    __syncthreads();
#pragma unroll
    for (int l = 0; l < 4; ++l)
        out[(size_t)(n0 + ty + 8 * l) * K + k0 + tx] = f2bf(t[tx][ty + 8 * l]);
}

// ---------------------------------------------------------------------------
// bf16 MFMA GEMM, fp32 out (+bias): C[M,N] = A[M,K] * Bt[N,K]^T   (128x128)
// ---------------------------------------------------------------------------
__global__ __launch_bounds__(256) void gemm_bf16(
    const unsigned short* __restrict__ A, const unsigned short* __restrict__ Bt,
    float* __restrict__ C, const float* __restrict__ bias, int M, int N, int K) {
    __shared__ short As[128 * 32];
    __shared__ short Bs[128 * 32];
    const int tid = threadIdx.x;
    const int w = tid >> 6, l = tid & 63;
    const int bm = blockIdx.y * 128, bn = blockIdx.x * 128;
    const int wm = (w >> 1) * 64, wn = (w & 1) * 64;
    const int lrow = l & 15, lq = l >> 4;

    f32x4 acc[4][4];
#pragma unroll
    for (int i = 0; i < 4; ++i)
#pragma unroll
        for (int j = 0; j < 4; ++j) acc[i][j] = (f32x4){0.f, 0.f, 0.f, 0.f};

    for (int k0 = 0; k0 < K; k0 += 32) {
#pragma unroll
        for (int t = 0; t < 2; ++t) {
            const int q = w * 2 + t;
            const int li = q * 512 + l * 8;
            const int row = li >> 5, kc = li & 31;
            const unsigned short* ga = A + (size_t)(bm + row) * K + k0 + kc;
            __builtin_amdgcn_global_load_lds(
                (const AS1 void*)ga, (AS3 void*)(As + q * 512), 16, 0, 0);
            const unsigned short* gb = Bt + (size_t)(bn + row) * K + k0 + kc;
            __builtin_amdgcn_global_load_lds(
                (const AS1 void*)gb, (AS3 void*)(Bs + q * 512), 16, 0, 0);
        }
        __syncthreads();

        short8 a[4], b[4];
#pragma unroll
        for (int i = 0; i < 4; ++i)
            a[i] = *(const short8*)(As + (wm + i * 16 + lrow) * 32 + lq * 8);
#pragma unroll
        for (int j = 0; j < 4; ++j)
            b[j] = *(const short8*)(Bs + (wn + j * 16 + lrow) * 32 + lq * 8);
#pragma unroll
        for (int i = 0; i < 4; ++i)
#pragma unroll
            for (int j = 0; j < 4; ++j)
                acc[i][j] = __builtin_amdgcn_mfma_f32_16x16x32_bf16(a[i], b[j], acc[i][j], 0, 0, 0);
        __syncthreads();
    }

#pragma unroll
    for (int i = 0; i < 4; ++i)
#pragma unroll
        for (int j = 0; j < 4; ++j) {
            const int col = bn + wn + j * 16 + lrow;
            const float bv = bias ? bias[col] : 0.f;
#pragma unroll
            for (int r = 0; r < 4; ++r) {
                const int row = bm + wm + i * 16 + lq * 4 + r;
                C[(size_t)row * N + col] = acc[i][j][r] + bv;
            }
        }
}

// ---------------------------------------------------------------------------
// 256x256-tile bf16 GEMM, bf16 out (QKV projection).
// 8 waves (2Mx4N), BK=32, phase-pipelined K-loop with counted vmcnt (T3+T4),
// st_16x32-style XOR swizzle (pre-swizzled global source + swizzled ds_read,
// same involution both sides), raw s_barrier (no vmcnt(0) drain in main loop),
// setprio around MFMA cluster (T5).
//
// LDS: 2 slots x (A 256x32 + B 256x32) bf16 = 64KB static.
// Region layout (shorts): slot*16384 + {A:0,B:8192} + half*4096 + rg*512,
// subtile = 16 rows x 32 cols, element (r,c) at phys = (r*32+c) ^ ((r&8)<<1).
//
// Staging cadence for tile t (slot s=t&1), one half-tile per phase:
//   p0: A-half0(t+1)->slot s^1   p1: A-half1(t+1)->slot s^1
//   p2: B-half0(t+2)->slot s     p3: B-half1(t+2)->slot s
// Per-wave vmcnt FIFO at p3: [B01(t+1)(2), A01(t+1)(2), B01(t+2)(2)] = 6
// outstanding -> s_waitcnt vmcnt(2) guarantees tile t+1 fully landed.
// ---------------------------------------------------------------------------
__device__ __forceinline__ void stage_st(const unsigned short* __restrict__ G, int K,
                                         int row0, int kt, short* dst_half,
                                         int w, int l) {
    const int grow = row0 + w * 16 + (l >> 2);
    const int gcol = kt * 32 + (((l & 3) * 8) ^ ((l & 32) ? 16 : 0));
    __builtin_amdgcn_global_load_lds(
        (const AS1 void*)(G + (size_t)grow * K + gcol),
        (AS3 void*)(dst_half + w * 512), 16, 0, 0);
}

__global__ __launch_bounds__(512, 2) void gemm256_bf(
    const unsigned short* __restrict__ A, const unsigned short* __restrict__ Bt,
    unsigned short* __restrict__ C, int M, int N, int K) {
    __shared__ __align__(16) short lds_[2 * 16384];
    const int tid = threadIdx.x;
    const int w = tid >> 6, l = tid & 63;
    const int wm = w >> 2, wn = w & 3;          // 2 x 4 wave grid
    const int lrow = l & 15, lq = l >> 4;
    const int bm = blockIdx.y * 256, bn = blockIdx.x * 256;
    const int NT = K >> 5;                       // K-tiles of 32

    const int aoff = lrow * 32 + ((lq * 8) ^ ((lrow & 8) ? 16 : 0));
    const int bsub = (wn & 1) * 4;              // B rg base for this wave

    f32x4 acc[8][4];
#pragma unroll
    for (int i = 0; i < 8; ++i)
#pragma unroll
        for (int j = 0; j < 4; ++j) acc[i][j] = (f32x4){0.f, 0.f, 0.f, 0.f};

    // ---- prologue: tile0 A+B, tile1 B; wait first 4 groups ----
    stage_st(A,  K, bm,       0, lds_ + 0,                    w, l);
    stage_st(A,  K, bm + 128, 0, lds_ + 4096,                 w, l);
    stage_st(Bt, K, bn,       0, lds_ + 8192,                 w, l);
    stage_st(Bt, K, bn + 128, 0, lds_ + 8192 + 4096,          w, l);
    stage_st(Bt, K, bn,       1, lds_ + 16384 + 8192,         w, l);
    stage_st(Bt, K, bn + 128, 1, lds_ + 16384 + 8192 + 4096,  w, l);
    asm volatile("s_waitcnt vmcnt(2)" ::: "memory");
    __builtin_amdgcn_s_barrier();

    for (int t = 0; t < NT; ++t) {
        const int s = t & 1;
        const short* Ah = lds_ + s * 16384 + wm * 4096;
        const short* Bh = lds_ + s * 16384 + 8192 + (wn >> 1) * 4096;
        short8 bfr[4];
#pragma unroll
        for (int p = 0; p < 4; ++p) {
            short8 a0 = *(const short8*)(Ah + (2 * p) * 512 + aoff);
            short8 a1 = *(const short8*)(Ah + (2 * p + 1) * 512 + aoff);
            if (p == 0) {
#pragma unroll
                for (int fc = 0; fc < 4; ++fc)
                    bfr[fc] = *(const short8*)(Bh + (bsub + fc) * 512 + aoff);
            }
            if (p == 0 && t + 1 < NT)
                stage_st(A,  K, bm,       t + 1, lds_ + (s ^ 1) * 16384,               w, l);
            if (p == 1 && t + 1 < NT)
                stage_st(A,  K, bm + 128, t + 1, lds_ + (s ^ 1) * 16384 + 4096,        w, l);
            if (p == 2 && t + 2 < NT)
                stage_st(Bt, K, bn,       t + 2, lds_ + s * 16384 + 8192,              w, l);
            if (p == 3 && t + 2 < NT)
                stage_st(Bt, K, bn + 128, t + 2, lds_ + s * 16384 + 8192 + 4096,       w, l);

            __builtin_amdgcn_s_barrier();
            asm volatile("s_waitcnt lgkmcnt(0)" ::: "memory");
            __builtin_amdgcn_sched_barrier(0);   // rule #18: pin MFMA below the wait

            __builtin_amdgcn_s_setprio(1);
#pragma unroll
            for (int fc = 0; fc < 4; ++fc) {
                acc[2 * p][fc] =
                    __builtin_amdgcn_mfma_f32_16x16x32_bf16(a0, bfr[fc], acc[2 * p][fc], 0, 0, 0);
                acc[2 * p + 1][fc] =
                    __builtin_amdgcn_mfma_f32_16x16x32_bf16(a1, bfr[fc], acc[2 * p + 1][fc], 0, 0, 0);
            }
            __builtin_amdgcn_s_setprio(0);

            if (p == 3) {
                if (t == NT - 2)
                    asm volatile("s_waitcnt vmcnt(0)" ::: "memory");
                else if (t < NT - 2)
                    asm volatile("s_waitcnt vmcnt(2)" ::: "memory");
            }
            __builtin_amdgcn_s_barrier();
        }
    }

    // ---- epilogue: bf16 C ----
#pragma unroll
    for (int fr = 0; fr < 8; ++fr)
#pragma unroll
        for (int fc = 0; fc < 4; ++fc) {
            const int col = bn + wn * 64 + fc * 16 + lrow;
#pragma unroll
            for (int r = 0; r < 4; ++r) {
                const int row = bm + wm * 128 + fr * 16 + lq * 4 + r;
                C[(size_t)row * N + col] = f2bf(acc[fr][fc][r]);
            }
        }
}

// ---------------------------------------------------------------------------
// STREAMING scores: j-split x2, 4-deep register prefetch, no max-sub.
// XCD-locality grid (R9): bh = blockIdx.x so the 16 blocks (8 i0 x 2 jh)
// sharing one head's K land on the same XCD L2 (linear id % 8 == bh % 8);
// K per XCD = 16 heads x 64KB = 1MB, L2-resident -> cuts the 4x cross-XCD
// K refetch and converts HBM-latency stalls into L2 hits.
// ---------------------------------------------------------------------------
__global__ __launch_bounds__(256) void scores_stream(
    const unsigned short* __restrict__ qkvb, unsigned short* __restrict__ attnb,
    float* __restrict__ lsum2) {
    const int bh = blockIdx.x;
    const int h = bh & 15, b = bh >> 4;
    const int jh = blockIdx.y;                 // j half: 0 or 1
    const int w = threadIdx.x >> 6, l = threadIdx.x & 63;
    const int i0 = blockIdx.z * 64 + w * 16;   // wave-private 16-row i-tile
    const int lrow = l & 15, lq = l >> 4;

    const unsigned short* qb = qkvb + (size_t)(b * NN) * QKV3 + h * DH + lq * 8;
    const unsigned short* kb = qkvb + (size_t)(b * NN) * QKV3 + INNER + h * DH + lq * 8;

    const short8 qf0 = *(const short8*)(qb + (size_t)(i0 + lrow) * QKV3);
    const short8 qf1 = *(const short8*)(qb + (size_t)(i0 + lrow) * QKV3 + 32);

    const unsigned short* krow = kb + (size_t)(jh * 256 + lrow) * QKV3;
    unsigned short* orow = attnb + (size_t)bh * PSTR + (size_t)(i0 + lrow) * NN +
                           jh * 256 + lq * 4;

    short8 ka[4], kc[4];
#pragma unroll
    for (int p = 0; p < 4; ++p) {
        const unsigned short* kp = krow + (size_t)p * 16 * QKV3;
        ka[p] = *(const short8*)(kp);
        kc[p] = *(const short8*)(kp + 32);
    }

    float lacc = 0.f;
#pragma unroll
    for (int jt = 0; jt < 16; ++jt) {
        const int s = jt & 3;
        short8 kf0 = ka[s], kf1 = kc[s];
        if (jt < 12) {
            const unsigned short* kp = krow + (size_t)(jt + 4) * 16 * QKV3;
            ka[s] = *(const short8*)(kp);
            kc[s] = *(const short8*)(kp + 32);
        }
        f32x4 acc = (f32x4){0.f, 0.f, 0.f, 0.f};
        acc = __builtin_amdgcn_mfma_f32_16x16x32_bf16(kf0, qf0, acc, 0, 0, 0);
        acc = __builtin_amdgcn_mfma_f32_16x16x32_bf16(kf1, qf1, acc, 0, 0, 0);
        float e0 = __expf(acc[0] * 0.125f);
        float e1 = __expf(acc[1] * 0.125f);
        float e2 = __expf(acc[2] * 0.125f);
        float e3 = __expf(acc[3] * 0.125f);
        lacc += (e0 + e1) + (e2 + e3);
        ushort4 o;
        o.x = f2bf(e0); o.y = f2bf(e1); o.z = f2bf(e2); o.w = f2bf(e3);
        *(ushort4*)(orow + jt * 16) = o;
    }
    lacc += __shfl_xor(lacc, 16, 64);
    lacc += __shfl_xor(lacc, 32, 64);
    if (lq == 0)
        lsum2[(size_t)jh * BB * HH * NN + (size_t)bh * NN + i0 + lrow] = lacc;
}

// ---------------------------------------------------------------------------
// Re-attention + LN over heads, bf16 in/out (fp32 math), 4 j per thread.
// Inputs are UNNORMALIZED exp values; scale by 1/(l0+l1) on load.
// attn planes at PADDED stride PSTR (de-aliases the 16-plane gather).
// ---------------------------------------------------------------------------
__global__ void reattn_ln_bf(unsigned short* __restrict__ attnb,
                             const float* __restrict__ lsum2,
                             const float* __restrict__ rw,
                             const float* __restrict__ gamma,
                             const float* __restrict__ beta) {
    __shared__ float w[16][16];
    __shared__ float gs[16], bs[16];
    const int tid = threadIdx.x;
    ((float*)w)[tid] = rw[tid];
    if (tid < 16) { gs[tid] = gamma[tid]; bs[tid] = beta[tid]; }
    __syncthreads();

    const size_t idx = (size_t)blockIdx.x * 256 + tid;  // over B*N*N/4
    const int j4 = (int)(idx & 127);
    const int i = (int)((idx >> 7) & 511);
    const int b = (int)(idx >> 16);
    unsigned short* base = attnb + (size_t)(b * HH) * PSTR + (size_t)i * NN + j4 * 4;
    const float* l0 = lsum2 + (size_t)(b * HH) * NN + i;
    const float* l1 = l0 + (size_t)BB * HH * NN;

    float v[16][4];
#pragma unroll
    for (int h = 0; h < 16; ++h) {
        const float linv = 1.0f / (l0[h * NN] + l1[h * NN]);
        ushort4 u = *(const ushort4*)(base + (size_t)h * PSTR);
        v[h][0] = bf2f(u.x) * linv; v[h][1] = bf2f(u.y) * linv;
        v[h][2] = bf2f(u.z) * linv; v[h][3] = bf2f(u.w) * linv;
    }
    float o[16][4];
    float me[4] = {0.f, 0.f, 0.f, 0.f};
#pragma unroll
    for (int g = 0; g < 16; ++g) {
        float s0 = 0.f, s1 = 0.f, s2 = 0.f, s3 = 0.f;
#pragma unroll
        for (int h = 0; h < 16; ++h) {
            const float wg = w[h][g];
            s0 += v[h][0] * wg; s1 += v[h][1] * wg;
            s2 += v[h][2] * wg; s3 += v[h][3] * wg;
        }
        o[g][0] = s0; o[g][1] = s1; o[g][2] = s2; o[g][3] = s3;
        me[0] += s0; me[1] += s1; me[2] += s2; me[3] += s3;
    }
#pragma unroll
    for (int r = 0; r < 4; ++r) me[r] *= 0.0625f;
    float va[4] = {0.f, 0.f, 0.f, 0.f};
#pragma unroll
    for (int g = 0; g < 16; ++g)
#pragma unroll
        for (int r = 0; r < 4; ++r) {
            float d = o[g][r] - me[r];
            va[r] += d * d;
        }
    float ri[4];
#pragma unroll
    for (int r = 0; r < 4; ++r) ri[r] = rsqrtf(va[r] * 0.0625f + 1e-3f);
#pragma unroll
    for (int g = 0; g < 16; ++g) {
        ushort4 u;
        u.x = f2bf((o[g][0] - me[0]) * ri[0] * gs[g] + bs[g]);
        u.y = f2bf((o[g][1] - me[1]) * ri[1] * gs[g] + bs[g]);
        u.z = f2bf((o[g][2] - me[2]) * ri[2] * gs[g] + bs[g]);
        u.w = f2bf((o[g][3] - me[3]) * ri[3] * gs[g] + bs[g]);
        *(ushort4*)(base + (size_t)g * PSTR) = u;
    }
}

// ---------------------------------------------------------------------------
// V transpose: qkvb [b,j,2048+h*64+d] -> vT [bh, d, j] (bf16)
// ---------------------------------------------------------------------------
__global__ void transpose_v(const unsigned short* __restrict__ qkvb,
                            unsigned short* __restrict__ vT) {
    __shared__ unsigned short t[32][33];
    const int bh = blockIdx.z;
    const int h = bh & 15, b = bh >> 4;
    const int j0 = blockIdx.x * 32, d0 = blockIdx.y * 32;
    const int tx = threadIdx.x & 31, ty = threadIdx.x >> 5;
    const unsigned short* src = qkvb + (size_t)(b * NN) * QKV3 + 2 * INNER + h * DH;
#pragma unroll
    for (int k = 0; k < 4; ++k)
        t[ty + 8 * k][tx] = src[(size_t)(j0 + ty + 8 * k) * QKV3 + d0 + tx];
    __syncthreads();
    unsigned short* dst = vT + (size_t)bh * DH * NN;
#pragma unroll
    for (int k = 0; k < 4; ++k)
        dst[(size_t)(d0 + ty + 8 * k) * NN + j0 + tx] = t[tx][ty + 8 * k];
}

// ---------------------------------------------------------------------------
// PV MFMA: outh[b,i,h*64+d] = sum_j P[bh,i,j] V[bh,j,d], P bf16 (padded
// plane stride), vT bf16. Transposed-D: lane holds col i, rows d.
// XCD-locality grid (R9): bh = blockIdx.x so the 4 i0-blocks sharing one
// vT plane (64KB) land on the same XCD L2.
// ---------------------------------------------------------------------------
__global__ __launch_bounds__(256) void pv_mfma(
    const unsigned short* __restrict__ attnb, const unsigned short* __restrict__ vT,
    unsigned short* __restrict__ outhb) {
    const int bh = blockIdx.x;
    const int h = bh & 15, b = bh >> 4;
    const int i0 = blockIdx.y * 128;
    __shared__ short Ps[128 * 64];
    __shared__ short Vs[64 * 64];
    const int tid = threadIdx.x;
    const int w = tid >> 6, l = tid & 63;
    const int lrow = l & 15, lq = l >> 4;
    const int lr8 = l >> 3;
    const int swd = ((l & 7) ^ (lr8 & 7)) * 8;

    f32x4 acc[2][4];
#pragma unroll
    for (int ic = 0; ic < 2; ++ic)
#pragma unroll
        for (int dt = 0; dt < 4; ++dt) acc[ic][dt] = (f32x4){0.f, 0.f, 0.f, 0.f};

    const unsigned short* pb = attnb + (size_t)bh * PSTR + (size_t)i0 * NN;
    const unsigned short* vb = vT + (size_t)bh * DH * NN;

    for (int j0 = 0; j0 < NN; j0 += 64) {
#pragma unroll
        for (int t = 0; t < 4; ++t) {
            int c = w * 4 + t;
            int r = c * 8 + lr8;
            __builtin_amdgcn_global_load_lds(
                (const AS1 void*)(pb + (size_t)r * NN + j0 + swd),
                (AS3 void*)(Ps + c * 512), 16, 0, 0);
        }
#pragma unroll
        for (int t = 0; t < 2; ++t) {
            int c = w * 2 + t;
            int d = c * 8 + lr8;
            __builtin_amdgcn_global_load_lds(
                (const AS1 void*)(vb + (size_t)d * NN + j0 + swd),
                (AS3 void*)(Vs + c * 512), 16, 0, 0);
        }
        __syncthreads();

#pragma unroll
        for (int kh = 0; kh < 2; ++kh) {
            short8 vf[4];
#pragma unroll
            for (int dt = 0; dt < 4; ++dt)
                vf[dt] = *(const short8*)(Vs + (dt * 16 + lrow) * 64 + (((kh * 4 + lq) ^ (lrow & 7)) * 8));
#pragma unroll
            for (int ic = 0; ic < 2; ++ic) {
                short8 pf = *(const short8*)(Ps + (w * 32 + ic * 16 + lrow) * 64 + (((kh * 4 + lq) ^ (lrow & 7)) * 8));
#pragma unroll
                for (int dt = 0; dt < 4; ++dt)
                    acc[ic][dt] = __builtin_amdgcn_mfma_f32_16x16x32_bf16(vf[dt], pf, acc[ic][dt], 0, 0, 0);
            }
        }
        __syncthreads();
    }

#pragma unroll
    for (int ic = 0; ic < 2; ++ic) {
        unsigned short* orow = outhb +
            ((size_t)(b * NN + i0 + w * 32 + ic * 16 + lrow)) * INNER + h * DH + lq * 4;
#pragma unroll
        for (int dt = 0; dt < 4; ++dt) {
            ushort4 o;
            o.x = f2bf(acc[ic][dt][0]); o.y = f2bf(acc[ic][dt][1]);
            o.z = f2bf(acc[ic][dt][2]); o.w = f2bf(acc[ic][dt][3]);
            *(ushort4*)(orow + dt * 16) = o;
        }
    }
}

// ---------------------------------------------------------------------------
extern "C" void kernel_launch(void* const* d_in, const int* in_sizes, int n_in,
                              void* d_out, int out_size, void* d_ws, size_t ws_size,
                              hipStream_t stream) {
    const float* x        = (const float*)d_in[0];
    const float* w_qkv    = (const float*)d_in[1];
    const float* reattn_w = (const float*)d_in[2];
    const float* ln_gamma = (const float*)d_in[3];
    const float* ln_beta  = (const float*)d_in[4];
    const float* w_out    = (const float*)d_in[5];
    const float* b_out    = (const float*)d_in[6];
    float* out = (float*)d_out;

    unsigned short* qkvb  = (unsigned short*)d_ws;                 // 12.58M
    unsigned short* attnb = qkvb + (size_t)BB * NN * QKV3;         // 128 * PSTR
    unsigned short* vTb   = attnb + (size_t)BB * HH * PSTR;        // 4.19M
    unsigned short* outhb = vTb + (size_t)BB * HH * DH * NN;       // 4.19M
    unsigned short* xb    = outhb + (size_t)BB * NN * INNER;       // 4.19M
    unsigned short* wqkvT = xb + (size_t)BB * NN * DD;             // 3.15M
    unsigned short* woutT = wqkvT + (size_t)DD * QKV3;             // 1.05M
    float*          lsum2 = (float*)(woutT + (size_t)INNER * INNER);  // 2*B*H*N f32

    dim3 blk(256);

    conv_bf16<<<dim3((BB * NN * DD) / 1024), blk, 0, stream>>>(x, xb);
    convT_bf16<<<dim3(QKV3 / 32, DD / 32), blk, 0, stream>>>(w_qkv, wqkvT, DD, QKV3);
    convT_bf16<<<dim3(INNER / 32, INNER / 32), blk, 0, stream>>>(w_out, woutT, INNER, INNER);

    // QKV projection -> bf16 (256^2-tile phase-pipelined GEMM, 512 threads)
    gemm256_bf<<<dim3(QKV3 / 256, (BB * NN) / 256), dim3(512), 0, stream>>>(
        xb, wqkvT, qkvb, BB * NN, QKV3, DD);

    // streaming scores: unnormalized exp -> attn bf16 (padded planes)
    // XCD-locality grid: bh fastest so same-head blocks share an XCD L2
    scores_stream<<<dim3(BB * HH, 2, NN / 64), blk, 0, stream>>>(qkvb, attnb, lsum2);

    // re-attention + LN (normalizes by 1/(l0+l1) on load, in-place bf16)
    reattn_ln_bf<<<dim3((BB * NN * NN) / 1024), blk, 0, stream>>>(
        attnb, lsum2, reattn_w, ln_gamma, ln_beta);

    // V transpose -> [bh][d][j]
    transpose_v<<<dim3(NN / 32, DH / 32, BB * HH), blk, 0, stream>>>(qkvb, vTb);

    // P @ V -> outh bf16 (bh fastest for vT L2 locality)
    pv_mfma<<<dim3(BB * HH, NN / 128), blk, 0, stream>>>(attnb, vTb, outhb);

    // output projection + bias (fp32 out)
    gemm_bf16<<<dim3(INNER / 128, (BB * NN) / 128), blk, 0, stream>>>(
        outhb, woutT, out, b_out, BB * NN, INNER, INNER);
}

// Round 5
// 236.269 us; speedup vs baseline: 1.0381x; 1.0090x over previous
//
#include <hip/hip_runtime.h>
#include <math.h>

#define BB 8
#define NN 512
#define DD 1024
#define HH 16
#define DH 64
#define INNER 1024
#define QKV3 3072
// attn head-plane stride in shorts: N*N + 64 (128B pad) breaks the exact
// 512KB power-of-2 stride that aliases all 16 head planes onto the same
// L2-set/HBM-channel group in reattn_ln_bf's 16-plane gather.
#define PSTR (NN * NN + 64)

typedef __attribute__((ext_vector_type(8))) short short8;
typedef __attribute__((ext_vector_type(4))) float f32x4;

#define AS1 __attribute__((address_space(1)))
#define AS3 __attribute__((address_space(3)))

__device__ __forceinline__ float4 ld4(const float* p) { return *(const float4*)p; }

__device__ __forceinline__ unsigned short f2bf(float f) {
    unsigned u = __float_as_uint(f);
    return (unsigned short)((u + 0x7fffu + ((u >> 16) & 1u)) >> 16);
}
__device__ __forceinline__ float bf2f(unsigned short u) {
    return __uint_as_float(((unsigned)u) << 16);
}

// ---------------------------------------------------------------------------
// fp32 -> bf16 elementwise convert (4 els/thread)
// ---------------------------------------------------------------------------
__global__ void conv_bf16(const float* __restrict__ in, unsigned short* __restrict__ out) {
    size_t i = ((size_t)blockIdx.x * 256 + threadIdx.x) * 4;
    float4 v = ld4(in + i);
    ushort4 o;
    o.x = f2bf(v.x); o.y = f2bf(v.y); o.z = f2bf(v.z); o.w = f2bf(v.w);
    *(ushort4*)(out + i) = o;
}

// ---------------------------------------------------------------------------
// fp32 [K][N] -> bf16 [N][K] transpose-convert, 32x32 LDS tiles
// ---------------------------------------------------------------------------
__global__ void convT_bf16(const float* __restrict__ in, unsigned short* __restrict__ out,
                           int K, int N) {
    __shared__ float t[32][33];
    const int n0 = blockIdx.x * 32, k0 = blockIdx.y * 32;
    const int tx = threadIdx.x & 31, ty = threadIdx.x >> 5;  // 32 x 8
#pragma unroll
    for (int l = 0; l < 4; ++l)
        t[ty + 8 * l][tx] = in[(size_t)(k0 + ty + 8 * l) * N + n0 + tx];
    __syncthreads();
#pragma unroll
    for (int l = 0; l < 4; ++l)
        out[(size_t)(n0 + ty + 8 * l) * K + k0 + tx] = f2bf(t[tx][ty + 8 * l]);
}

// ---------------------------------------------------------------------------
// bf16 MFMA GEMM, fp32 out (+bias): C[M,N] = A[M,K] * Bt[N,K]^T   (128x128)
// ---------------------------------------------------------------------------
__global__ __launch_bounds__(256) void gemm_bf16(
    const unsigned short* __restrict__ A, const unsigned short* __restrict__ Bt,
    float* __restrict__ C, const float* __restrict__ bias, int M, int N, int K) {
    __shared__ short As[128 * 32];
    __shared__ short Bs[128 * 32];
    const int tid = threadIdx.x;
    const int w = tid >> 6, l = tid & 63;
    const int bm = blockIdx.y * 128, bn = blockIdx.x * 128;
    const int wm = (w >> 1) * 64, wn = (w & 1) * 64;
    const int lrow = l & 15, lq = l >> 4;

    f32x4 acc[4][4];
#pragma unroll
    for (int i = 0; i < 4; ++i)
#pragma unroll
        for (int j = 0; j < 4; ++j) acc[i][j] = (f32x4){0.f, 0.f, 0.f, 0.f};

    for (int k0 = 0; k0 < K; k0 += 32) {
#pragma unroll
        for (int t = 0; t < 2; ++t) {
            const int q = w * 2 + t;
            const int li = q * 512 + l * 8;
            const int row = li >> 5, kc = li & 31;
            const unsigned short* ga = A + (size_t)(bm + row) * K + k0 + kc;
            __builtin_amdgcn_global_load_lds(
                (const AS1 void*)ga, (AS3 void*)(As + q * 512), 16, 0, 0);
            const unsigned short* gb = Bt + (size_t)(bn + row) * K + k0 + kc;
            __builtin_amdgcn_global_load_lds(
                (const AS1 void*)gb, (AS3 void*)(Bs + q * 512), 16, 0, 0);
        }
        __syncthreads();

        short8 a[4], b[4];
#pragma unroll
        for (int i = 0; i < 4; ++i)
            a[i] = *(const short8*)(As + (wm + i * 16 + lrow) * 32 + lq * 8);
#pragma unroll
        for (int j = 0; j < 4; ++j)
            b[j] = *(const short8*)(Bs + (wn + j * 16 + lrow) * 32 + lq * 8);
#pragma unroll
        for (int i = 0; i < 4; ++i)
#pragma unroll
            for (int j = 0; j < 4; ++j)
                acc[i][j] = __builtin_amdgcn_mfma_f32_16x16x32_bf16(a[i], b[j], acc[i][j], 0, 0, 0);
        __syncthreads();
    }

#pragma unroll
    for (int i = 0; i < 4; ++i)
#pragma unroll
        for (int j = 0; j < 4; ++j) {
            const int col = bn + wn + j * 16 + lrow;
            const float bv = bias ? bias[col] : 0.f;
#pragma unroll
            for (int r = 0; r < 4; ++r) {
                const int row = bm + wm + i * 16 + lq * 4 + r;
                C[(size_t)row * N + col] = acc[i][j][r] + bv;
            }
        }
}

// ---------------------------------------------------------------------------
// 256x256-tile bf16 GEMM, bf16 out (QKV projection).
// 8 waves (2Mx4N), BK=32, phase-pipelined K-loop with counted vmcnt (T3+T4),
// st_16x32-style XOR swizzle, raw s_barrier, setprio around MFMA (T5).
// LDS: 2 slots x (A 256x32 + B 256x32) bf16 = 64KB static.
// ---------------------------------------------------------------------------
__device__ __forceinline__ void stage_st(const unsigned short* __restrict__ G, int K,
                                         int row0, int kt, short* dst_half,
                                         int w, int l) {
    const int grow = row0 + w * 16 + (l >> 2);
    const int gcol = kt * 32 + (((l & 3) * 8) ^ ((l & 32) ? 16 : 0));
    __builtin_amdgcn_global_load_lds(
        (const AS1 void*)(G + (size_t)grow * K + gcol),
        (AS3 void*)(dst_half + w * 512), 16, 0, 0);
}

__global__ __launch_bounds__(512, 2) void gemm256_bf(
    const unsigned short* __restrict__ A, const unsigned short* __restrict__ Bt,
    unsigned short* __restrict__ C, int M, int N, int K) {
    __shared__ __align__(16) short lds_[2 * 16384];
    const int tid = threadIdx.x;
    const int w = tid >> 6, l = tid & 63;
    const int wm = w >> 2, wn = w & 3;          // 2 x 4 wave grid
    const int lrow = l & 15, lq = l >> 4;
    const int bm = blockIdx.y * 256, bn = blockIdx.x * 256;
    const int NT = K >> 5;                       // K-tiles of 32

    const int aoff = lrow * 32 + ((lq * 8) ^ ((lrow & 8) ? 16 : 0));
    const int bsub = (wn & 1) * 4;              // B rg base for this wave

    f32x4 acc[8][4];
#pragma unroll
    for (int i = 0; i < 8; ++i)
#pragma unroll
        for (int j = 0; j < 4; ++j) acc[i][j] = (f32x4){0.f, 0.f, 0.f, 0.f};

    // ---- prologue: tile0 A+B, tile1 B; wait first 4 groups ----
    stage_st(A,  K, bm,       0, lds_ + 0,                    w, l);
    stage_st(A,  K, bm + 128, 0, lds_ + 4096,                 w, l);
    stage_st(Bt, K, bn,       0, lds_ + 8192,                 w, l);
    stage_st(Bt, K, bn + 128, 0, lds_ + 8192 + 4096,          w, l);
    stage_st(Bt, K, bn,       1, lds_ + 16384 + 8192,         w, l);
    stage_st(Bt, K, bn + 128, 1, lds_ + 16384 + 8192 + 4096,  w, l);
    asm volatile("s_waitcnt vmcnt(2)" ::: "memory");
    __builtin_amdgcn_s_barrier();

    for (int t = 0; t < NT; ++t) {
        const int s = t & 1;
        const short* Ah = lds_ + s * 16384 + wm * 4096;
        const short* Bh = lds_ + s * 16384 + 8192 + (wn >> 1) * 4096;
        short8 bfr[4];
#pragma unroll
        for (int p = 0; p < 4; ++p) {
            short8 a0 = *(const short8*)(Ah + (2 * p) * 512 + aoff);
            short8 a1 = *(const short8*)(Ah + (2 * p + 1) * 512 + aoff);
            if (p == 0) {
#pragma unroll
                for (int fc = 0; fc < 4; ++fc)
                    bfr[fc] = *(const short8*)(Bh + (bsub + fc) * 512 + aoff);
            }
            if (p == 0 && t + 1 < NT)
                stage_st(A,  K, bm,       t + 1, lds_ + (s ^ 1) * 16384,               w, l);
            if (p == 1 && t + 1 < NT)
                stage_st(A,  K, bm + 128, t + 1, lds_ + (s ^ 1) * 16384 + 4096,        w, l);
            if (p == 2 && t + 2 < NT)
                stage_st(Bt, K, bn,       t + 2, lds_ + s * 16384 + 8192,              w, l);
            if (p == 3 && t + 2 < NT)
                stage_st(Bt, K, bn + 128, t + 2, lds_ + s * 16384 + 8192 + 4096,       w, l);

            __builtin_amdgcn_s_barrier();
            asm volatile("s_waitcnt lgkmcnt(0)" ::: "memory");
            __builtin_amdgcn_sched_barrier(0);   // rule #18: pin MFMA below the wait

            __builtin_amdgcn_s_setprio(1);
#pragma unroll
            for (int fc = 0; fc < 4; ++fc) {
                acc[2 * p][fc] =
                    __builtin_amdgcn_mfma_f32_16x16x32_bf16(a0, bfr[fc], acc[2 * p][fc], 0, 0, 0);
                acc[2 * p + 1][fc] =
                    __builtin_amdgcn_mfma_f32_16x16x32_bf16(a1, bfr[fc], acc[2 * p + 1][fc], 0, 0, 0);
            }
            __builtin_amdgcn_s_setprio(0);

            if (p == 3) {
                if (t == NT - 2)
                    asm volatile("s_waitcnt vmcnt(0)" ::: "memory");
                else if (t < NT - 2)
                    asm volatile("s_waitcnt vmcnt(2)" ::: "memory");
            }
            __builtin_amdgcn_s_barrier();
        }
    }

    // ---- epilogue: bf16 C ----
#pragma unroll
    for (int fr = 0; fr < 8; ++fr)
#pragma unroll
        for (int fc = 0; fc < 4; ++fc) {
            const int col = bn + wn * 64 + fc * 16 + lrow;
#pragma unroll
            for (int r = 0; r < 4; ++r) {
                const int row = bm + wm * 128 + fr * 16 + lq * 4 + r;
                C[(size_t)row * N + col] = f2bf(acc[fr][fc][r]);
            }
        }
}

// ---------------------------------------------------------------------------
// STREAMING scores: j-split x2, 4-deep register prefetch, no max-sub.
// XCD-locality grid (R9): bh = blockIdx.x -> same-head blocks share an XCD L2
// (FETCH 37->8.6MB, verified R4).
// R10: LDS store-staging. The direct acc->global store scattered 8B/lane
// across 16 rows (1KB stride) = 16 partial 32B transactions per store inst,
// 4096/wave -> store-issue serialization was the 42us floor. Now each wave
// buffers its 16x256 tile in wave-private LDS (row padded to 264 shorts to
// spread the 512B-stride ds_write across 8 banks), then flushes with
// fully-coalesced 512B row stores (16 stores/wave, 8 lines each = 32x fewer
// write transactions). Wave-private -> no __syncthreads needed.
// ---------------------------------------------------------------------------
__global__ __launch_bounds__(256) void scores_stream(
    const unsigned short* __restrict__ qkvb, unsigned short* __restrict__ attnb,
    float* __restrict__ lsum2) {
    __shared__ unsigned short obuf[4][16][264];   // 33KB, wave-private slabs
    const int bh = blockIdx.x;
    const int h = bh & 15, b = bh >> 4;
    const int jh = blockIdx.y;                 // j half: 0 or 1
    const int w = threadIdx.x >> 6, l = threadIdx.x & 63;
    const int i0 = blockIdx.z * 64 + w * 16;   // wave-private 16-row i-tile
    const int lrow = l & 15, lq = l >> 4;

    const unsigned short* qb = qkvb + (size_t)(b * NN) * QKV3 + h * DH + lq * 8;
    const unsigned short* kb = qkvb + (size_t)(b * NN) * QKV3 + INNER + h * DH + lq * 8;

    const short8 qf0 = *(const short8*)(qb + (size_t)(i0 + lrow) * QKV3);
    const short8 qf1 = *(const short8*)(qb + (size_t)(i0 + lrow) * QKV3 + 32);

    const unsigned short* krow = kb + (size_t)(jh * 256 + lrow) * QKV3;

    short8 ka[4], kc[4];
#pragma unroll
    for (int p = 0; p < 4; ++p) {
        const unsigned short* kp = krow + (size_t)p * 16 * QKV3;
        ka[p] = *(const short8*)(kp);
        kc[p] = *(const short8*)(kp + 32);
    }

    float lacc = 0.f;
#pragma unroll
    for (int jt = 0; jt < 16; ++jt) {
        const int s = jt & 3;
        short8 kf0 = ka[s], kf1 = kc[s];
        if (jt < 12) {
            const unsigned short* kp = krow + (size_t)(jt + 4) * 16 * QKV3;
            ka[s] = *(const short8*)(kp);
            kc[s] = *(const short8*)(kp + 32);
        }
        f32x4 acc = (f32x4){0.f, 0.f, 0.f, 0.f};
        acc = __builtin_amdgcn_mfma_f32_16x16x32_bf16(kf0, qf0, acc, 0, 0, 0);
        acc = __builtin_amdgcn_mfma_f32_16x16x32_bf16(kf1, qf1, acc, 0, 0, 0);
        float e0 = __expf(acc[0] * 0.125f);
        float e1 = __expf(acc[1] * 0.125f);
        float e2 = __expf(acc[2] * 0.125f);
        float e3 = __expf(acc[3] * 0.125f);
        lacc += (e0 + e1) + (e2 + e3);
        ushort4 o;
        o.x = f2bf(e0); o.y = f2bf(e1); o.z = f2bf(e2); o.w = f2bf(e3);
        *(ushort4*)(&obuf[w][lrow][jt * 16 + lq * 4]) = o;
    }
    lacc += __shfl_xor(lacc, 16, 64);
    lacc += __shfl_xor(lacc, 32, 64);
    if (lq == 0)
        lsum2[(size_t)jh * BB * HH * NN + (size_t)bh * NN + i0 + lrow] = lacc;

    // coalesced flush: one 512B row per store (wave-private data, no barrier)
    unsigned short* obase = attnb + (size_t)bh * PSTR + (size_t)i0 * NN + jh * 256;
#pragma unroll
    for (int r = 0; r < 16; ++r)
        *(ushort4*)(obase + (size_t)r * NN + l * 4) =
            *(const ushort4*)(&obuf[w][r][l * 4]);
}

// ---------------------------------------------------------------------------
// Re-attention + LN over heads, bf16 in/out (fp32 math), 4 j per thread.
// Inputs are UNNORMALIZED exp values; scale by 1/(l0+l1) on load.
// attn planes at PADDED stride PSTR (de-aliases the 16-plane gather).
// ---------------------------------------------------------------------------
__global__ void reattn_ln_bf(unsigned short* __restrict__ attnb,
                             const float* __restrict__ lsum2,
                             const float* __restrict__ rw,
                             const float* __restrict__ gamma,
                             const float* __restrict__ beta) {
    __shared__ float w[16][16];
    __shared__ float gs[16], bs[16];
    const int tid = threadIdx.x;
    ((float*)w)[tid] = rw[tid];
    if (tid < 16) { gs[tid] = gamma[tid]; bs[tid] = beta[tid]; }
    __syncthreads();

    const size_t idx = (size_t)blockIdx.x * 256 + tid;  // over B*N*N/4
    const int j4 = (int)(idx & 127);
    const int i = (int)((idx >> 7) & 511);
    const int b = (int)(idx >> 16);
    unsigned short* base = attnb + (size_t)(b * HH) * PSTR + (size_t)i * NN + j4 * 4;
    const float* l0 = lsum2 + (size_t)(b * HH) * NN + i;
    const float* l1 = l0 + (size_t)BB * HH * NN;

    float v[16][4];
#pragma unroll
    for (int h = 0; h < 16; ++h) {
        const float linv = 1.0f / (l0[h * NN] + l1[h * NN]);
        ushort4 u = *(const ushort4*)(base + (size_t)h * PSTR);
        v[h][0] = bf2f(u.x) * linv; v[h][1] = bf2f(u.y) * linv;
        v[h][2] = bf2f(u.z) * linv; v[h][3] = bf2f(u.w) * linv;
    }
    float o[16][4];
    float me[4] = {0.f, 0.f, 0.f, 0.f};
#pragma unroll
    for (int g = 0; g < 16; ++g) {
        float s0 = 0.f, s1 = 0.f, s2 = 0.f, s3 = 0.f;
#pragma unroll
        for (int h = 0; h < 16; ++h) {
            const float wg = w[h][g];
            s0 += v[h][0] * wg; s1 += v[h][1] * wg;
            s2 += v[h][2] * wg; s3 += v[h][3] * wg;
        }
        o[g][0] = s0; o[g][1] = s1; o[g][2] = s2; o[g][3] = s3;
        me[0] += s0; me[1] += s1; me[2] += s2; me[3] += s3;
    }
#pragma unroll
    for (int r = 0; r < 4; ++r) me[r] *= 0.0625f;
    float va[4] = {0.f, 0.f, 0.f, 0.f};
#pragma unroll
    for (int g = 0; g < 16; ++g)
#pragma unroll
        for (int r = 0; r < 4; ++r) {
            float d = o[g][r] - me[r];
            va[r] += d * d;
        }
    float ri[4];
#pragma unroll
    for (int r = 0; r < 4; ++r) ri[r] = rsqrtf(va[r] * 0.0625f + 1e-3f);
#pragma unroll
    for (int g = 0; g < 16; ++g) {
        ushort4 u;
        u.x = f2bf((o[g][0] - me[0]) * ri[0] * gs[g] + bs[g]);
        u.y = f2bf((o[g][1] - me[1]) * ri[1] * gs[g] + bs[g]);
        u.z = f2bf((o[g][2] - me[2]) * ri[2] * gs[g] + bs[g]);
        u.w = f2bf((o[g][3] - me[3]) * ri[3] * gs[g] + bs[g]);
        *(ushort4*)(base + (size_t)g * PSTR) = u;
    }
}

// ---------------------------------------------------------------------------
// V transpose: qkvb [b,j,2048+h*64+d] -> vT [bh, d, j] (bf16)
// ---------------------------------------------------------------------------
__global__ void transpose_v(const unsigned short* __restrict__ qkvb,
                            unsigned short* __restrict__ vT) {
    __shared__ unsigned short t[32][33];
    const int bh = blockIdx.z;
    const int h = bh & 15, b = bh >> 4;
    const int j0 = blockIdx.x * 32, d0 = blockIdx.y * 32;
    const int tx = threadIdx.x & 31, ty = threadIdx.x >> 5;
    const unsigned short* src = qkvb + (size_t)(b * NN) * QKV3 + 2 * INNER + h * DH;
#pragma unroll
    for (int k = 0; k < 4; ++k)
        t[ty + 8 * k][tx] = src[(size_t)(j0 + ty + 8 * k) * QKV3 + d0 + tx];
    __syncthreads();
    unsigned short* dst = vT + (size_t)bh * DH * NN;
#pragma unroll
    for (int k = 0; k < 4; ++k)
        dst[(size_t)(d0 + ty + 8 * k) * NN + j0 + tx] = t[tx][ty + 8 * k];
}

// ---------------------------------------------------------------------------
// PV MFMA: outh[b,i,h*64+d] = sum_j P[bh,i,j] V[bh,j,d], P bf16 (padded
// plane stride), vT bf16. Transposed-D: lane holds col i, rows d.
// XCD-locality grid (R9): bh = blockIdx.x.
// ---------------------------------------------------------------------------
__global__ __launch_bounds__(256) void pv_mfma(
    const unsigned short* __restrict__ attnb, const unsigned short* __restrict__ vT,
    unsigned short* __restrict__ outhb) {
    const int bh = blockIdx.x;
    const int h = bh & 15, b = bh >> 4;
    const int i0 = blockIdx.y * 128;
    __shared__ short Ps[128 * 64];
    __shared__ short Vs[64 * 64];
    const int tid = threadIdx.x;
    const int w = tid >> 6, l = tid & 63;
    const int lrow = l & 15, lq = l >> 4;
    const int lr8 = l >> 3;
    const int swd = ((l & 7) ^ (lr8 & 7)) * 8;

    f32x4 acc[2][4];
#pragma unroll
    for (int ic = 0; ic < 2; ++ic)
#pragma unroll
        for (int dt = 0; dt < 4; ++dt) acc[ic][dt] = (f32x4){0.f, 0.f, 0.f, 0.f};

    const unsigned short* pb = attnb + (size_t)bh * PSTR + (size_t)i0 * NN;
    const unsigned short* vb = vT + (size_t)bh * DH * NN;

    for (int j0 = 0; j0 < NN; j0 += 64) {
#pragma unroll
        for (int t = 0; t < 4; ++t) {
            int c = w * 4 + t;
            int r = c * 8 + lr8;
            __builtin_amdgcn_global_load_lds(
                (const AS1 void*)(pb + (size_t)r * NN + j0 + swd),
                (AS3 void*)(Ps + c * 512), 16, 0, 0);
        }
#pragma unroll
        for (int t = 0; t < 2; ++t) {
            int c = w * 2 + t;
            int d = c * 8 + lr8;
            __builtin_amdgcn_global_load_lds(
                (const AS1 void*)(vb + (size_t)d * NN + j0 + swd),
                (AS3 void*)(Vs + c * 512), 16, 0, 0);
        }
        __syncthreads();

#pragma unroll
        for (int kh = 0; kh < 2; ++kh) {
            short8 vf[4];
#pragma unroll
            for (int dt = 0; dt < 4; ++dt)
                vf[dt] = *(const short8*)(Vs + (dt * 16 + lrow) * 64 + (((kh * 4 + lq) ^ (lrow & 7)) * 8));
#pragma unroll
            for (int ic = 0; ic < 2; ++ic) {
                short8 pf = *(const short8*)(Ps + (w * 32 + ic * 16 + lrow) * 64 + (((kh * 4 + lq) ^ (lrow & 7)) * 8));
#pragma unroll
                for (int dt = 0; dt < 4; ++dt)
                    acc[ic][dt] = __builtin_amdgcn_mfma_f32_16x16x32_bf16(vf[dt], pf, acc[ic][dt], 0, 0, 0);
            }
        }
        __syncthreads();
    }

#pragma unroll
    for (int ic = 0; ic < 2; ++ic) {
        unsigned short* orow = outhb +
            ((size_t)(b * NN + i0 + w * 32 + ic * 16 + lrow)) * INNER + h * DH + lq * 4;
#pragma unroll
        for (int dt = 0; dt < 4; ++dt) {
            ushort4 o;
            o.x = f2bf(acc[ic][dt][0]); o.y = f2bf(acc[ic][dt][1]);
            o.z = f2bf(acc[ic][dt][2]); o.w = f2bf(acc[ic][dt][3]);
            *(ushort4*)(orow + dt * 16) = o;
        }
    }
}

// ---------------------------------------------------------------------------
extern "C" void kernel_launch(void* const* d_in, const int* in_sizes, int n_in,
                              void* d_out, int out_size, void* d_ws, size_t ws_size,
                              hipStream_t stream) {
    const float* x        = (const float*)d_in[0];
    const float* w_qkv    = (const float*)d_in[1];
    const float* reattn_w = (const float*)d_in[2];
    const float* ln_gamma = (const float*)d_in[3];
    const float* ln_beta  = (const float*)d_in[4];
    const float* w_out    = (const float*)d_in[5];
    const float* b_out    = (const float*)d_in[6];
    float* out = (float*)d_out;

    unsigned short* qkvb  = (unsigned short*)d_ws;                 // 12.58M
    unsigned short* attnb = qkvb + (size_t)BB * NN * QKV3;         // 128 * PSTR
    unsigned short* vTb   = attnb + (size_t)BB * HH * PSTR;        // 4.19M
    unsigned short* outhb = vTb + (size_t)BB * HH * DH * NN;       // 4.19M
    unsigned short* xb    = outhb + (size_t)BB * NN * INNER;       // 4.19M
    unsigned short* wqkvT = xb + (size_t)BB * NN * DD;             // 3.15M
    unsigned short* woutT = wqkvT + (size_t)DD * QKV3;             // 1.05M
    float*          lsum2 = (float*)(woutT + (size_t)INNER * INNER);  // 2*B*H*N f32

    dim3 blk(256);

    conv_bf16<<<dim3((BB * NN * DD) / 1024), blk, 0, stream>>>(x, xb);
    convT_bf16<<<dim3(QKV3 / 32, DD / 32), blk, 0, stream>>>(w_qkv, wqkvT, DD, QKV3);
    convT_bf16<<<dim3(INNER / 32, INNER / 32), blk, 0, stream>>>(w_out, woutT, INNER, INNER);

    // QKV projection -> bf16 (256^2-tile phase-pipelined GEMM, 512 threads)
    gemm256_bf<<<dim3(QKV3 / 256, (BB * NN) / 256), dim3(512), 0, stream>>>(
        xb, wqkvT, qkvb, BB * NN, QKV3, DD);

    // streaming scores: unnormalized exp -> attn bf16 (padded planes)
    // XCD-locality grid: bh fastest so same-head blocks share an XCD L2
    scores_stream<<<dim3(BB * HH, 2, NN / 64), blk, 0, stream>>>(qkvb, attnb, lsum2);

    // re-attention + LN (normalizes by 1/(l0+l1) on load, in-place bf16)
    reattn_ln_bf<<<dim3((BB * NN * NN) / 1024), blk, 0, stream>>>(
        attnb, lsum2, reattn_w, ln_gamma, ln_beta);

    // V transpose -> [bh][d][j]
    transpose_v<<<dim3(NN / 32, DH / 32, BB * HH), blk, 0, stream>>>(qkvb, vTb);

    // P @ V -> outh bf16 (bh fastest for vT L2 locality)
    pv_mfma<<<dim3(BB * HH, NN / 128), blk, 0, stream>>>(attnb, vTb, outhb);

    // output projection + bias (fp32 out)
    gemm_bf16<<<dim3(INNER / 128, (BB * NN) / 128), blk, 0, stream>>>(
        outhb, woutT, out, b_out, BB * NN, INNER, INNER);
}

// Round 6
// 219.187 us; speedup vs baseline: 1.1190x; 1.0779x over previous
//
#include <hip/hip_runtime.h>
#include <math.h>

#define BB 8
#define NN 512
#define DD 1024
#define HH 16
#define DH 64
#define INNER 1024
#define QKV3 3072
// attn head-plane stride in shorts: N*N + 64 (128B pad) breaks the exact
// 512KB power-of-2 stride that aliases all 16 head planes onto the same
// L2-set/HBM-channel group in reattn_ln_bf's 16-plane gather.
#define PSTR (NN * NN + 64)

typedef __attribute__((ext_vector_type(8))) short short8;
typedef __attribute__((ext_vector_type(4))) float f32x4;

#define AS1 __attribute__((address_space(1)))
#define AS3 __attribute__((address_space(3)))

__device__ __forceinline__ float4 ld4(const float* p) { return *(const float4*)p; }

__device__ __forceinline__ unsigned short f2bf(float f) {
    unsigned u = __float_as_uint(f);
    return (unsigned short)((u + 0x7fffu + ((u >> 16) & 1u)) >> 16);
}
__device__ __forceinline__ float bf2f(unsigned short u) {
    return __uint_as_float(((unsigned)u) << 16);
}

// ---------------------------------------------------------------------------
// fp32 -> bf16 elementwise convert (4 els/thread)
// ---------------------------------------------------------------------------
__global__ void conv_bf16(const float* __restrict__ in, unsigned short* __restrict__ out) {
    size_t i = ((size_t)blockIdx.x * 256 + threadIdx.x) * 4;
    float4 v = ld4(in + i);
    ushort4 o;
    o.x = f2bf(v.x); o.y = f2bf(v.y); o.z = f2bf(v.z); o.w = f2bf(v.w);
    *(ushort4*)(out + i) = o;
}

// ---------------------------------------------------------------------------
// fp32 [K][N] -> bf16 [N][K] transpose-convert, 32x32 LDS tiles
// ---------------------------------------------------------------------------
__global__ void convT_bf16(const float* __restrict__ in, unsigned short* __restrict__ out,
                           int K, int N) {
    __shared__ float t[32][33];
    const int n0 = blockIdx.x * 32, k0 = blockIdx.y * 32;
    const int tx = threadIdx.x & 31, ty = threadIdx.x >> 5;  // 32 x 8
#pragma unroll
    for (int l = 0; l < 4; ++l)
        t[ty + 8 * l][tx] = in[(size_t)(k0 + ty + 8 * l) * N + n0 + tx];
    __syncthreads();
#pragma unroll
    for (int l = 0; l < 4; ++l)
        out[(size_t)(n0 + ty + 8 * l) * K + k0 + tx] = f2bf(t[tx][ty + 8 * l]);
}

// ---------------------------------------------------------------------------
// bf16 MFMA GEMM, fp32 out (+bias): C[M,N] = A[M,K] * Bt[N,K]^T   (128x128)
// ---------------------------------------------------------------------------
__global__ __launch_bounds__(256) void gemm_bf16(
    const unsigned short* __restrict__ A, const unsigned short* __restrict__ Bt,
    float* __restrict__ C, const float* __restrict__ bias, int M, int N, int K) {
    __shared__ short As[128 * 32];
    __shared__ short Bs[128 * 32];
    const int tid = threadIdx.x;
    const int w = tid >> 6, l = tid & 63;
    const int bm = blockIdx.y * 128, bn = blockIdx.x * 128;
    const int wm = (w >> 1) * 64, wn = (w & 1) * 64;
    const int lrow = l & 15, lq = l >> 4;

    f32x4 acc[4][4];
#pragma unroll
    for (int i = 0; i < 4; ++i)
#pragma unroll
        for (int j = 0; j < 4; ++j) acc[i][j] = (f32x4){0.f, 0.f, 0.f, 0.f};

    for (int k0 = 0; k0 < K; k0 += 32) {
#pragma unroll
        for (int t = 0; t < 2; ++t) {
            const int q = w * 2 + t;
            const int li = q * 512 + l * 8;
            const int row = li >> 5, kc = li & 31;
            const unsigned short* ga = A + (size_t)(bm + row) * K + k0 + kc;
            __builtin_amdgcn_global_load_lds(
                (const AS1 void*)ga, (AS3 void*)(As + q * 512), 16, 0, 0);
            const unsigned short* gb = Bt + (size_t)(bn + row) * K + k0 + kc;
            __builtin_amdgcn_global_load_lds(
                (const AS1 void*)gb, (AS3 void*)(Bs + q * 512), 16, 0, 0);
        }
        __syncthreads();

        short8 a[4], b[4];
#pragma unroll
        for (int i = 0; i < 4; ++i)
            a[i] = *(const short8*)(As + (wm + i * 16 + lrow) * 32 + lq * 8);
#pragma unroll
        for (int j = 0; j < 4; ++j)
            b[j] = *(const short8*)(Bs + (wn + j * 16 + lrow) * 32 + lq * 8);
#pragma unroll
        for (int i = 0; i < 4; ++i)
#pragma unroll
            for (int j = 0; j < 4; ++j)
                acc[i][j] = __builtin_amdgcn_mfma_f32_16x16x32_bf16(a[i], b[j], acc[i][j], 0, 0, 0);
        __syncthreads();
    }

#pragma unroll
    for (int i = 0; i < 4; ++i)
#pragma unroll
        for (int j = 0; j < 4; ++j) {
            const int col = bn + wn + j * 16 + lrow;
            const float bv = bias ? bias[col] : 0.f;
#pragma unroll
            for (int r = 0; r < 4; ++r) {
                const int row = bm + wm + i * 16 + lq * 4 + r;
                C[(size_t)row * N + col] = acc[i][j][r] + bv;
            }
        }
}

// ---------------------------------------------------------------------------
// 256x256-tile bf16 GEMM, bf16 out (QKV projection).  v2 (R11):
// 8 waves (2Mx4N), BK=32, ONE barrier per K-tile (T3 "minimum 2-phase"):
//   stage A+B(t+1) -> slot s^1 FIRST (async, in flight under reads+MFMA)
//   12 ds_reads of slot s -> lgkmcnt(0) -> 32-MFMA cluster (setprio)
//   vmcnt(0) (stages issued ~350cyc ago, mostly landed) -> s_barrier
// Rationale: 192 blocks on 256 CUs = 1 resident block/CU, so the old
// 8-barriers-per-K-tile lockstep had no co-resident block to hide behind
// (R5: MfmaUtil 23.6%, Occupancy 13.9%).
// Single-barrier safety: each wave's ds_reads of s^1 complete before its
// lgkmcnt(0), which precedes its barrier arrival in iter t-1 -> iter t's
// async writes to s^1 cannot race any wave's reads.
// LDS: 2 slots x (A 256x32 + B 256x32) bf16 = 64KB static.
// ---------------------------------------------------------------------------
__device__ __forceinline__ void stage_st(const unsigned short* __restrict__ G, int K,
                                         int row0, int kt, short* dst_half,
                                         int w, int l) {
    const int grow = row0 + w * 16 + (l >> 2);
    const int gcol = kt * 32 + (((l & 3) * 8) ^ ((l & 32) ? 16 : 0));
    __builtin_amdgcn_global_load_lds(
        (const AS1 void*)(G + (size_t)grow * K + gcol),
        (AS3 void*)(dst_half + w * 512), 16, 0, 0);
}

__global__ __launch_bounds__(512, 2) void gemm256_bf(
    const unsigned short* __restrict__ A, const unsigned short* __restrict__ Bt,
    unsigned short* __restrict__ C, int M, int N, int K) {
    __shared__ __align__(16) short lds_[2 * 16384];
    const int tid = threadIdx.x;
    const int w = tid >> 6, l = tid & 63;
    const int wm = w >> 2, wn = w & 3;          // 2 x 4 wave grid
    const int lrow = l & 15, lq = l >> 4;
    const int bm = blockIdx.y * 256, bn = blockIdx.x * 256;
    const int NT = K >> 5;                       // K-tiles of 32

    const int aoff = lrow * 32 + ((lq * 8) ^ ((lrow & 8) ? 16 : 0));
    const int bsub = (wn & 1) * 4;              // B rg base for this wave

    f32x4 acc[8][4];
#pragma unroll
    for (int i = 0; i < 8; ++i)
#pragma unroll
        for (int j = 0; j < 4; ++j) acc[i][j] = (f32x4){0.f, 0.f, 0.f, 0.f};

    // ---- prologue: tile 0 into slot 0 ----
    stage_st(A,  K, bm,       0, lds_ + 0,     w, l);
    stage_st(A,  K, bm + 128, 0, lds_ + 4096,  w, l);
    stage_st(Bt, K, bn,       0, lds_ + 8192,  w, l);
    stage_st(Bt, K, bn + 128, 0, lds_ + 12288, w, l);
    asm volatile("s_waitcnt vmcnt(0)" ::: "memory");
    __builtin_amdgcn_s_barrier();

    for (int t = 0; t < NT; ++t) {
        const int s = t & 1;
        // stage next tile first (HBM latency hides under ds_reads + MFMA)
        if (t + 1 < NT) {
            short* nb = lds_ + (s ^ 1) * 16384;
            stage_st(A,  K, bm,       t + 1, nb,         w, l);
            stage_st(A,  K, bm + 128, t + 1, nb + 4096,  w, l);
            stage_st(Bt, K, bn,       t + 1, nb + 8192,  w, l);
            stage_st(Bt, K, bn + 128, t + 1, nb + 12288, w, l);
        }
        const short* Ah = lds_ + s * 16384 + wm * 4096;
        const short* Bh = lds_ + s * 16384 + 8192 + (wn >> 1) * 4096;
        short8 a[8], bfr[4];
#pragma unroll
        for (int i = 0; i < 8; ++i)
            a[i] = *(const short8*)(Ah + i * 512 + aoff);
#pragma unroll
        for (int j = 0; j < 4; ++j)
            bfr[j] = *(const short8*)(Bh + (bsub + j) * 512 + aoff);

        asm volatile("s_waitcnt lgkmcnt(0)" ::: "memory");
        __builtin_amdgcn_sched_barrier(0);   // rule #18: pin MFMA below the wait

        __builtin_amdgcn_s_setprio(1);
#pragma unroll
        for (int i = 0; i < 8; ++i)
#pragma unroll
            for (int j = 0; j < 4; ++j)
                acc[i][j] = __builtin_amdgcn_mfma_f32_16x16x32_bf16(a[i], bfr[j], acc[i][j], 0, 0, 0);
        __builtin_amdgcn_s_setprio(0);

        asm volatile("s_waitcnt vmcnt(0)" ::: "memory");
        __builtin_amdgcn_s_barrier();
    }

    // ---- epilogue: bf16 C ----
#pragma unroll
    for (int fr = 0; fr < 8; ++fr)
#pragma unroll
        for (int fc = 0; fc < 4; ++fc) {
            const int col = bn + wn * 64 + fc * 16 + lrow;
#pragma unroll
            for (int r = 0; r < 4; ++r) {
                const int row = bm + wm * 128 + fr * 16 + lq * 4 + r;
                C[(size_t)row * N + col] = f2bf(acc[fr][fc][r]);
            }
        }
}

// ---------------------------------------------------------------------------
// STREAMING scores v3 (R11): K-half staged in LDS via global_load_lds.
// R5 showed VGPR_Count=32 -> the old "4-deep register prefetch" never
// materialized (needs 40+ VGPRs); loads sank to right-before-use and every
// jt iteration ate exposed L2/HBM latency. global_load_lds needs NO dest
// VGPRs and the 4 waves share the same 32KB K-half (was 4x redundant).
// K LDS layout: [256 rows][8 chunks of 16B], chunk XOR-preswizzled with
// (row&7) on the global SOURCE; ds_read applies the same XOR (rule #21).
// Output staged in obuf (64-col chunks), flushed every 4 jt as 128B
// contiguous row-runs (full-line coalesced). LDS 41.5KB -> 3 blocks/CU.
// XCD-locality grid (R9): bh = blockIdx.x (FETCH 37->8.6MB, verified R4).
// ---------------------------------------------------------------------------
__global__ __launch_bounds__(256) void scores_stream(
    const unsigned short* __restrict__ qkvb, unsigned short* __restrict__ attnb,
    float* __restrict__ lsum2) {
    __shared__ unsigned short Ks[256 * 64];       // 32KB K-half, swizzled
    __shared__ unsigned short obuf[4][16][68];    // 8.7KB wave-private out chunks
    const int bh = blockIdx.x;
    const int h = bh & 15, b = bh >> 4;
    const int jh = blockIdx.y;                 // j half: 0 or 1
    const int w = threadIdx.x >> 6, l = threadIdx.x & 63;
    const int i0 = blockIdx.z * 64 + w * 16;   // wave-private 16-row i-tile
    const int lrow = l & 15, lq = l >> 4;

    // ---- stage K-half: 256 rows x 128B, 8 insts/wave, pre-swizzled source ----
    const unsigned short* kbase =
        qkvb + (size_t)(b * NN + jh * 256) * QKV3 + INNER + h * DH;
#pragma unroll
    for (int i = 0; i < 8; ++i) {
        const int r = (w * 8 + i) * 8 + (l >> 3);   // row this lane covers
        const int c = (l & 7) ^ (r & 7);            // inverse-swizzled chunk
        __builtin_amdgcn_global_load_lds(
            (const AS1 void*)(kbase + (size_t)r * QKV3 + c * 8),
            (AS3 void*)(Ks + (w * 8 + i) * 512), 16, 0, 0);
    }

    const unsigned short* qb = qkvb + (size_t)(b * NN) * QKV3 + h * DH + lq * 8;
    const short8 qf0 = *(const short8*)(qb + (size_t)(i0 + lrow) * QKV3);
    const short8 qf1 = *(const short8*)(qb + (size_t)(i0 + lrow) * QKV3 + 32);

    asm volatile("s_waitcnt vmcnt(0)" ::: "memory");
    __syncthreads();

    unsigned short* obase = attnb + (size_t)bh * PSTR + (size_t)i0 * NN + jh * 256;
    const int sw = lrow & 7;                     // per-lane read swizzle
    float lacc = 0.f;
#pragma unroll
    for (int jt = 0; jt < 16; ++jt) {
        const int R = jt * 16 + lrow;
        const short8 kf0 = *(const short8*)(Ks + R * 64 + ((lq ^ sw) * 8));
        const short8 kf1 = *(const short8*)(Ks + R * 64 + (((4 + lq) ^ sw) * 8));
        f32x4 acc = (f32x4){0.f, 0.f, 0.f, 0.f};
        acc = __builtin_amdgcn_mfma_f32_16x16x32_bf16(kf0, qf0, acc, 0, 0, 0);
        acc = __builtin_amdgcn_mfma_f32_16x16x32_bf16(kf1, qf1, acc, 0, 0, 0);
        float e0 = __expf(acc[0] * 0.125f);
        float e1 = __expf(acc[1] * 0.125f);
        float e2 = __expf(acc[2] * 0.125f);
        float e3 = __expf(acc[3] * 0.125f);
        lacc += (e0 + e1) + (e2 + e3);
        ushort4 o;
        o.x = f2bf(e0); o.y = f2bf(e1); o.z = f2bf(e2); o.w = f2bf(e3);
        *(ushort4*)(&obuf[w][lrow][(jt & 3) * 16 + lq * 4]) = o;
        if ((jt & 3) == 3) {
            // flush 16 rows x 64 cols: 4 stores, each 4 rows x 128B runs
            const int jb = (jt >> 2) * 64;
#pragma unroll
            for (int q = 0; q < 4; ++q) {
                const int rr = q * 4 + (l >> 4);
                const int cc = l & 15;
                *(ushort4*)(obase + (size_t)rr * NN + jb + cc * 4) =
                    *(const ushort4*)(&obuf[w][rr][cc * 4]);
            }
        }
    }
    lacc += __shfl_xor(lacc, 16, 64);
    lacc += __shfl_xor(lacc, 32, 64);
    if (lq == 0)
        lsum2[(size_t)jh * BB * HH * NN + (size_t)bh * NN + i0 + lrow] = lacc;
}

// ---------------------------------------------------------------------------
// Re-attention + LN over heads, bf16 in/out (fp32 math), 4 j per thread.
// Inputs are UNNORMALIZED exp values; scale by 1/(l0+l1) on load.
// attn planes at PADDED stride PSTR (de-aliases the 16-plane gather).
// ---------------------------------------------------------------------------
__global__ void reattn_ln_bf(unsigned short* __restrict__ attnb,
                             const float* __restrict__ lsum2,
                             const float* __restrict__ rw,
                             const float* __restrict__ gamma,
                             const float* __restrict__ beta) {
    __shared__ float w[16][16];
    __shared__ float gs[16], bs[16];
    const int tid = threadIdx.x;
    ((float*)w)[tid] = rw[tid];
    if (tid < 16) { gs[tid] = gamma[tid]; bs[tid] = beta[tid]; }
    __syncthreads();

    const size_t idx = (size_t)blockIdx.x * 256 + tid;  // over B*N*N/4
    const int j4 = (int)(idx & 127);
    const int i = (int)((idx >> 7) & 511);
    const int b = (int)(idx >> 16);
    unsigned short* base = attnb + (size_t)(b * HH) * PSTR + (size_t)i * NN + j4 * 4;
    const float* l0 = lsum2 + (size_t)(b * HH) * NN + i;
    const float* l1 = l0 + (size_t)BB * HH * NN;

    float v[16][4];
#pragma unroll
    for (int h = 0; h < 16; ++h) {
        const float linv = 1.0f / (l0[h * NN] + l1[h * NN]);
        ushort4 u = *(const ushort4*)(base + (size_t)h * PSTR);
        v[h][0] = bf2f(u.x) * linv; v[h][1] = bf2f(u.y) * linv;
        v[h][2] = bf2f(u.z) * linv; v[h][3] = bf2f(u.w) * linv;
    }
    float o[16][4];
    float me[4] = {0.f, 0.f, 0.f, 0.f};
#pragma unroll
    for (int g = 0; g < 16; ++g) {
        float s0 = 0.f, s1 = 0.f, s2 = 0.f, s3 = 0.f;
#pragma unroll
        for (int h = 0; h < 16; ++h) {
            const float wg = w[h][g];
            s0 += v[h][0] * wg; s1 += v[h][1] * wg;
            s2 += v[h][2] * wg; s3 += v[h][3] * wg;
        }
        o[g][0] = s0; o[g][1] = s1; o[g][2] = s2; o[g][3] = s3;
        me[0] += s0; me[1] += s1; me[2] += s2; me[3] += s3;
    }
#pragma unroll
    for (int r = 0; r < 4; ++r) me[r] *= 0.0625f;
    float va[4] = {0.f, 0.f, 0.f, 0.f};
#pragma unroll
    for (int g = 0; g < 16; ++g)
#pragma unroll
        for (int r = 0; r < 4; ++r) {
            float d = o[g][r] - me[r];
            va[r] += d * d;
        }
    float ri[4];
#pragma unroll
    for (int r = 0; r < 4; ++r) ri[r] = rsqrtf(va[r] * 0.0625f + 1e-3f);
#pragma unroll
    for (int g = 0; g < 16; ++g) {
        ushort4 u;
        u.x = f2bf((o[g][0] - me[0]) * ri[0] * gs[g] + bs[g]);
        u.y = f2bf((o[g][1] - me[1]) * ri[1] * gs[g] + bs[g]);
        u.z = f2bf((o[g][2] - me[2]) * ri[2] * gs[g] + bs[g]);
        u.w = f2bf((o[g][3] - me[3]) * ri[3] * gs[g] + bs[g]);
        *(ushort4*)(base + (size_t)g * PSTR) = u;
    }
}

// ---------------------------------------------------------------------------
// V transpose: qkvb [b,j,2048+h*64+d] -> vT [bh, d, j] (bf16)
// ---------------------------------------------------------------------------
__global__ void transpose_v(const unsigned short* __restrict__ qkvb,
                            unsigned short* __restrict__ vT) {
    __shared__ unsigned short t[32][33];
    const int bh = blockIdx.z;
    const int h = bh & 15, b = bh >> 4;
    const int j0 = blockIdx.x * 32, d0 = blockIdx.y * 32;
    const int tx = threadIdx.x & 31, ty = threadIdx.x >> 5;
    const unsigned short* src = qkvb + (size_t)(b * NN) * QKV3 + 2 * INNER + h * DH;
#pragma unroll
    for (int k = 0; k < 4; ++k)
        t[ty + 8 * k][tx] = src[(size_t)(j0 + ty + 8 * k) * QKV3 + d0 + tx];
    __syncthreads();
    unsigned short* dst = vT + (size_t)bh * DH * NN;
#pragma unroll
    for (int k = 0; k < 4; ++k)
        dst[(size_t)(d0 + ty + 8 * k) * NN + j0 + tx] = t[tx][ty + 8 * k];
}

// ---------------------------------------------------------------------------
// PV MFMA: outh[b,i,h*64+d] = sum_j P[bh,i,j] V[bh,j,d], P bf16 (padded
// plane stride), vT bf16. Transposed-D: lane holds col i, rows d.
// XCD-locality grid (R9): bh = blockIdx.x.
// ---------------------------------------------------------------------------
__global__ __launch_bounds__(256) void pv_mfma(
    const unsigned short* __restrict__ attnb, const unsigned short* __restrict__ vT,
    unsigned short* __restrict__ outhb) {
    const int bh = blockIdx.x;
    const int h = bh & 15, b = bh >> 4;
    const int i0 = blockIdx.y * 128;
    __shared__ short Ps[128 * 64];
    __shared__ short Vs[64 * 64];
    const int tid = threadIdx.x;
    const int w = tid >> 6, l = tid & 63;
    const int lrow = l & 15, lq = l >> 4;
    const int lr8 = l >> 3;
    const int swd = ((l & 7) ^ (lr8 & 7)) * 8;

    f32x4 acc[2][4];
#pragma unroll
    for (int ic = 0; ic < 2; ++ic)
#pragma unroll
        for (int dt = 0; dt < 4; ++dt) acc[ic][dt] = (f32x4){0.f, 0.f, 0.f, 0.f};

    const unsigned short* pb = attnb + (size_t)bh * PSTR + (size_t)i0 * NN;
    const unsigned short* vb = vT + (size_t)bh * DH * NN;

    for (int j0 = 0; j0 < NN; j0 += 64) {
#pragma unroll
        for (int t = 0; t < 4; ++t) {
            int c = w * 4 + t;
            int r = c * 8 + lr8;
            __builtin_amdgcn_global_load_lds(
                (const AS1 void*)(pb + (size_t)r * NN + j0 + swd),
                (AS3 void*)(Ps + c * 512), 16, 0, 0);
        }
#pragma unroll
        for (int t = 0; t < 2; ++t) {
            int c = w * 2 + t;
            int d = c * 8 + lr8;
            __builtin_amdgcn_global_load_lds(
                (const AS1 void*)(vb + (size_t)d * NN + j0 + swd),
                (AS3 void*)(Vs + c * 512), 16, 0, 0);
        }
        __syncthreads();

#pragma unroll
        for (int kh = 0; kh < 2; ++kh) {
            short8 vf[4];
#pragma unroll
            for (int dt = 0; dt < 4; ++dt)
                vf[dt] = *(const short8*)(Vs + (dt * 16 + lrow) * 64 + (((kh * 4 + lq) ^ (lrow & 7)) * 8));
#pragma unroll
            for (int ic = 0; ic < 2; ++ic) {
                short8 pf = *(const short8*)(Ps + (w * 32 + ic * 16 + lrow) * 64 + (((kh * 4 + lq) ^ (lrow & 7)) * 8));
#pragma unroll
                for (int dt = 0; dt < 4; ++dt)
                    acc[ic][dt] = __builtin_amdgcn_mfma_f32_16x16x32_bf16(vf[dt], pf, acc[ic][dt], 0, 0, 0);
            }
        }
        __syncthreads();
    }

#pragma unroll
    for (int ic = 0; ic < 2; ++ic) {
        unsigned short* orow = outhb +
            ((size_t)(b * NN + i0 + w * 32 + ic * 16 + lrow)) * INNER + h * DH + lq * 4;
#pragma unroll
        for (int dt = 0; dt < 4; ++dt) {
            ushort4 o;
            o.x = f2bf(acc[ic][dt][0]); o.y = f2bf(acc[ic][dt][1]);
            o.z = f2bf(acc[ic][dt][2]); o.w = f2bf(acc[ic][dt][3]);
            *(ushort4*)(orow + dt * 16) = o;
        }
    }
}

// ---------------------------------------------------------------------------
extern "C" void kernel_launch(void* const* d_in, const int* in_sizes, int n_in,
                              void* d_out, int out_size, void* d_ws, size_t ws_size,
                              hipStream_t stream) {
    const float* x        = (const float*)d_in[0];
    const float* w_qkv    = (const float*)d_in[1];
    const float* reattn_w = (const float*)d_in[2];
    const float* ln_gamma = (const float*)d_in[3];
    const float* ln_beta  = (const float*)d_in[4];
    const float* w_out    = (const float*)d_in[5];
    const float* b_out    = (const float*)d_in[6];
    float* out = (float*)d_out;

    unsigned short* qkvb  = (unsigned short*)d_ws;                 // 12.58M
    unsigned short* attnb = qkvb + (size_t)BB * NN * QKV3;         // 128 * PSTR
    unsigned short* vTb   = attnb + (size_t)BB * HH * PSTR;        // 4.19M
    unsigned short* outhb = vTb + (size_t)BB * HH * DH * NN;       // 4.19M
    unsigned short* xb    = outhb + (size_t)BB * NN * INNER;       // 4.19M
    unsigned short* wqkvT = xb + (size_t)BB * NN * DD;             // 3.15M
    unsigned short* woutT = wqkvT + (size_t)DD * QKV3;             // 1.05M
    float*          lsum2 = (float*)(woutT + (size_t)INNER * INNER);  // 2*B*H*N f32

    dim3 blk(256);

    conv_bf16<<<dim3((BB * NN * DD) / 1024), blk, 0, stream>>>(x, xb);
    convT_bf16<<<dim3(QKV3 / 32, DD / 32), blk, 0, stream>>>(w_qkv, wqkvT, DD, QKV3);
    convT_bf16<<<dim3(INNER / 32, INNER / 32), blk, 0, stream>>>(w_out, woutT, INNER, INNER);

    // QKV projection -> bf16 (256^2-tile, 1-barrier-per-K-tile, 512 threads)
    gemm256_bf<<<dim3(QKV3 / 256, (BB * NN) / 256), dim3(512), 0, stream>>>(
        xb, wqkvT, qkvb, BB * NN, QKV3, DD);

    // streaming scores: unnormalized exp -> attn bf16 (padded planes)
    // XCD-locality grid: bh fastest so same-head blocks share an XCD L2
    scores_stream<<<dim3(BB * HH, 2, NN / 64), blk, 0, stream>>>(qkvb, attnb, lsum2);

    // re-attention + LN (normalizes by 1/(l0+l1) on load, in-place bf16)
    reattn_ln_bf<<<dim3((BB * NN * NN) / 1024), blk, 0, stream>>>(
        attnb, lsum2, reattn_w, ln_gamma, ln_beta);

    // V transpose -> [bh][d][j]
    transpose_v<<<dim3(NN / 32, DH / 32, BB * HH), blk, 0, stream>>>(qkvb, vTb);

    // P @ V -> outh bf16 (bh fastest for vT L2 locality)
    pv_mfma<<<dim3(BB * HH, NN / 128), blk, 0, stream>>>(attnb, vTb, outhb);

    // output projection + bias (fp32 out)
    gemm_bf16<<<dim3(INNER / 128, (BB * NN) / 128), blk, 0, stream>>>(
        outhb, woutT, out, b_out, BB * NN, INNER, INNER);
}

// Round 7
// 208.439 us; speedup vs baseline: 1.1767x; 1.0516x over previous
//
#include <hip/hip_runtime.h>
#include <math.h>

#define BB 8
#define NN 512
#define DD 1024
#define HH 16
#define DH 64
#define INNER 1024
#define QKV3 3072
// attn head-plane stride in shorts: N*N + 64 (128B pad) breaks the exact
// 512KB power-of-2 stride that aliases all 16 head planes onto the same
// L2-set/HBM-channel group in reattn_ln_bf's 16-plane gather.
#define PSTR (NN * NN + 64)

typedef __attribute__((ext_vector_type(8))) short short8;
typedef __attribute__((ext_vector_type(4))) float f32x4;

#define AS1 __attribute__((address_space(1)))
#define AS3 __attribute__((address_space(3)))

__device__ __forceinline__ float4 ld4(const float* p) { return *(const float4*)p; }

__device__ __forceinline__ unsigned short f2bf(float f) {
    unsigned u = __float_as_uint(f);
    return (unsigned short)((u + 0x7fffu + ((u >> 16) & 1u)) >> 16);
}
__device__ __forceinline__ float bf2f(unsigned short u) {
    return __uint_as_float(((unsigned)u) << 16);
}

// ---------------------------------------------------------------------------
// Merged preprocessing (R12): conv_bf16 + convT(w_qkv) + convT(w_out) in one
// launch (9 -> 7 graph nodes). Block partition: [0,4096) x->xb elementwise;
// [4096,7168) w_qkv transpose; [7168,8192) w_out transpose.
// ---------------------------------------------------------------------------
__global__ void preprocess(const float* __restrict__ x, unsigned short* __restrict__ xb,
                           const float* __restrict__ wq, unsigned short* __restrict__ wqT,
                           const float* __restrict__ wo, unsigned short* __restrict__ woT) {
    __shared__ float t[32][33];
    const int tid = threadIdx.x;
    const int bx = blockIdx.x;
    if (bx < 4096) {
        size_t i = ((size_t)bx * 256 + tid) * 4;
        float4 v = ld4(x + i);
        ushort4 o;
        o.x = f2bf(v.x); o.y = f2bf(v.y); o.z = f2bf(v.z); o.w = f2bf(v.w);
        *(ushort4*)(xb + i) = o;
        return;
    }
    const float* in; unsigned short* out; int K, N, n0, k0;
    if (bx < 7168) {
        const int bb = bx - 4096;
        in = wq; out = wqT; K = DD; N = QKV3;
        n0 = (bb % 96) * 32; k0 = (bb / 96) * 32;
    } else {
        const int bb = bx - 7168;
        in = wo; out = woT; K = INNER; N = INNER;
        n0 = (bb & 31) * 32; k0 = (bb >> 5) * 32;
    }
    const int tx = tid & 31, ty = tid >> 5;  // 32 x 8
#pragma unroll
    for (int l = 0; l < 4; ++l)
        t[ty + 8 * l][tx] = in[(size_t)(k0 + ty + 8 * l) * N + n0 + tx];
    __syncthreads();
#pragma unroll
    for (int l = 0; l < 4; ++l)
        out[(size_t)(n0 + ty + 8 * l) * K + k0 + tx] = f2bf(t[tx][ty + 8 * l]);
}

// ---------------------------------------------------------------------------
// bf16 MFMA GEMM, fp32 out (+bias): C[M,N] = A[M,K] * Bt[N,K]^T   (128x128)
// v2 (R12): 1-barrier-per-K-tile dbuf (same schedule proven on gemm256 in R6):
// stage(t+1)->slot s^1 first (async under reads+MFMA), ds_read frags of slot s,
// lgkmcnt(0)+sched_barrier (rule #18), 16-MFMA setprio cluster, vmcnt(0),
// single s_barrier. asm memory clobbers fence the compiler; slot-race safe
// (reads of s precede lgkm0 which precedes the barrier; writes to s issue
// only after it).  LDS: 2 slots x (A 128x32 + B 128x32) bf16 = 32KB.
// ---------------------------------------------------------------------------
__device__ __forceinline__ void stage128(const unsigned short* __restrict__ A,
                                         const unsigned short* __restrict__ Bt,
                                         int K, int bm, int bn, int kt,
                                         short* sb, int w, int l) {
#pragma unroll
    for (int t = 0; t < 2; ++t) {
        const int q = w * 2 + t;
        const int li = q * 512 + l * 8;
        const int row = li >> 5, kc = li & 31;
        __builtin_amdgcn_global_load_lds(
            (const AS1 void*)(A + (size_t)(bm + row) * K + kt * 32 + kc),
            (AS3 void*)(sb + q * 512), 16, 0, 0);
        __builtin_amdgcn_global_load_lds(
            (const AS1 void*)(Bt + (size_t)(bn + row) * K + kt * 32 + kc),
            (AS3 void*)(sb + 4096 + q * 512), 16, 0, 0);
    }
}

__global__ __launch_bounds__(256) void gemm_bf16(
    const unsigned short* __restrict__ A, const unsigned short* __restrict__ Bt,
    float* __restrict__ C, const float* __restrict__ bias, int M, int N, int K) {
    __shared__ __align__(16) short lds_[2 * 8192];   // 32KB
    const int tid = threadIdx.x;
    const int w = tid >> 6, l = tid & 63;
    const int bm = blockIdx.y * 128, bn = blockIdx.x * 128;
    const int wm = (w >> 1) * 64, wn = (w & 1) * 64;
    const int lrow = l & 15, lq = l >> 4;
    const int NT = K >> 5;

    f32x4 acc[4][4];
#pragma unroll
    for (int i = 0; i < 4; ++i)
#pragma unroll
        for (int j = 0; j < 4; ++j) acc[i][j] = (f32x4){0.f, 0.f, 0.f, 0.f};

    stage128(A, Bt, K, bm, bn, 0, lds_, w, l);
    asm volatile("s_waitcnt vmcnt(0)" ::: "memory");
    __builtin_amdgcn_s_barrier();

    for (int t = 0; t < NT; ++t) {
        const int s = t & 1;
        if (t + 1 < NT)
            stage128(A, Bt, K, bm, bn, t + 1, lds_ + (s ^ 1) * 8192, w, l);
        const short* As_ = lds_ + s * 8192;
        const short* Bs_ = As_ + 4096;
        short8 a[4], b[4];
#pragma unroll
        for (int i = 0; i < 4; ++i)
            a[i] = *(const short8*)(As_ + (wm + i * 16 + lrow) * 32 + lq * 8);
#pragma unroll
        for (int j = 0; j < 4; ++j)
            b[j] = *(const short8*)(Bs_ + (wn + j * 16 + lrow) * 32 + lq * 8);

        asm volatile("s_waitcnt lgkmcnt(0)" ::: "memory");
        __builtin_amdgcn_sched_barrier(0);

        __builtin_amdgcn_s_setprio(1);
#pragma unroll
        for (int i = 0; i < 4; ++i)
#pragma unroll
            for (int j = 0; j < 4; ++j)
                acc[i][j] = __builtin_amdgcn_mfma_f32_16x16x32_bf16(a[i], b[j], acc[i][j], 0, 0, 0);
        __builtin_amdgcn_s_setprio(0);

        asm volatile("s_waitcnt vmcnt(0)" ::: "memory");
        __builtin_amdgcn_s_barrier();
    }

#pragma unroll
    for (int i = 0; i < 4; ++i)
#pragma unroll
        for (int j = 0; j < 4; ++j) {
            const int col = bn + wn + j * 16 + lrow;
            const float bv = bias ? bias[col] : 0.f;
#pragma unroll
            for (int r = 0; r < 4; ++r) {
                const int row = bm + wm + i * 16 + lq * 4 + r;
                C[(size_t)row * N + col] = acc[i][j][r] + bv;
            }
        }
}

// ---------------------------------------------------------------------------
// 256x256-tile bf16 GEMM, bf16 out (QKV projection).  v2 (R11):
// 8 waves (2Mx4N), BK=32, ONE barrier per K-tile. Unchanged from R6.
// ---------------------------------------------------------------------------
__device__ __forceinline__ void stage_st(const unsigned short* __restrict__ G, int K,
                                         int row0, int kt, short* dst_half,
                                         int w, int l) {
    const int grow = row0 + w * 16 + (l >> 2);
    const int gcol = kt * 32 + (((l & 3) * 8) ^ ((l & 32) ? 16 : 0));
    __builtin_amdgcn_global_load_lds(
        (const AS1 void*)(G + (size_t)grow * K + gcol),
        (AS3 void*)(dst_half + w * 512), 16, 0, 0);
}

__global__ __launch_bounds__(512, 2) void gemm256_bf(
    const unsigned short* __restrict__ A, const unsigned short* __restrict__ Bt,
    unsigned short* __restrict__ C, int M, int N, int K) {
    __shared__ __align__(16) short lds_[2 * 16384];
    const int tid = threadIdx.x;
    const int w = tid >> 6, l = tid & 63;
    const int wm = w >> 2, wn = w & 3;          // 2 x 4 wave grid
    const int lrow = l & 15, lq = l >> 4;
    const int bm = blockIdx.y * 256, bn = blockIdx.x * 256;
    const int NT = K >> 5;                       // K-tiles of 32

    const int aoff = lrow * 32 + ((lq * 8) ^ ((lrow & 8) ? 16 : 0));
    const int bsub = (wn & 1) * 4;              // B rg base for this wave

    f32x4 acc[8][4];
#pragma unroll
    for (int i = 0; i < 8; ++i)
#pragma unroll
        for (int j = 0; j < 4; ++j) acc[i][j] = (f32x4){0.f, 0.f, 0.f, 0.f};

    // ---- prologue: tile 0 into slot 0 ----
    stage_st(A,  K, bm,       0, lds_ + 0,     w, l);
    stage_st(A,  K, bm + 128, 0, lds_ + 4096,  w, l);
    stage_st(Bt, K, bn,       0, lds_ + 8192,  w, l);
    stage_st(Bt, K, bn + 128, 0, lds_ + 12288, w, l);
    asm volatile("s_waitcnt vmcnt(0)" ::: "memory");
    __builtin_amdgcn_s_barrier();

    for (int t = 0; t < NT; ++t) {
        const int s = t & 1;
        if (t + 1 < NT) {
            short* nb = lds_ + (s ^ 1) * 16384;
            stage_st(A,  K, bm,       t + 1, nb,         w, l);
            stage_st(A,  K, bm + 128, t + 1, nb + 4096,  w, l);
            stage_st(Bt, K, bn,       t + 1, nb + 8192,  w, l);
            stage_st(Bt, K, bn + 128, t + 1, nb + 12288, w, l);
        }
        const short* Ah = lds_ + s * 16384 + wm * 4096;
        const short* Bh = lds_ + s * 16384 + 8192 + (wn >> 1) * 4096;
        short8 a[8], bfr[4];
#pragma unroll
        for (int i = 0; i < 8; ++i)
            a[i] = *(const short8*)(Ah + i * 512 + aoff);
#pragma unroll
        for (int j = 0; j < 4; ++j)
            bfr[j] = *(const short8*)(Bh + (bsub + j) * 512 + aoff);

        asm volatile("s_waitcnt lgkmcnt(0)" ::: "memory");
        __builtin_amdgcn_sched_barrier(0);   // rule #18: pin MFMA below the wait

        __builtin_amdgcn_s_setprio(1);
#pragma unroll
        for (int i = 0; i < 8; ++i)
#pragma unroll
            for (int j = 0; j < 4; ++j)
                acc[i][j] = __builtin_amdgcn_mfma_f32_16x16x32_bf16(a[i], bfr[j], acc[i][j], 0, 0, 0);
        __builtin_amdgcn_s_setprio(0);

        asm volatile("s_waitcnt vmcnt(0)" ::: "memory");
        __builtin_amdgcn_s_barrier();
    }

    // ---- epilogue: bf16 C ----
#pragma unroll
    for (int fr = 0; fr < 8; ++fr)
#pragma unroll
        for (int fc = 0; fc < 4; ++fc) {
            const int col = bn + wn * 64 + fc * 16 + lrow;
#pragma unroll
            for (int r = 0; r < 4; ++r) {
                const int row = bm + wm * 128 + fr * 16 + lq * 4 + r;
                C[(size_t)row * N + col] = f2bf(acc[fr][fc][r]);
            }
        }
}

// ---------------------------------------------------------------------------
// STREAMING scores v3 (R11): K-half staged in LDS via global_load_lds;
// XCD-locality grid; coalesced obuf flush. Unchanged from R6.
// ---------------------------------------------------------------------------
__global__ __launch_bounds__(256) void scores_stream(
    const unsigned short* __restrict__ qkvb, unsigned short* __restrict__ attnb,
    float* __restrict__ lsum2) {
    __shared__ unsigned short Ks[256 * 64];       // 32KB K-half, swizzled
    __shared__ unsigned short obuf[4][16][68];    // 8.7KB wave-private out chunks
    const int bh = blockIdx.x;
    const int h = bh & 15, b = bh >> 4;
    const int jh = blockIdx.y;                 // j half: 0 or 1
    const int w = threadIdx.x >> 6, l = threadIdx.x & 63;
    const int i0 = blockIdx.z * 64 + w * 16;   // wave-private 16-row i-tile
    const int lrow = l & 15, lq = l >> 4;

    // ---- stage K-half: 256 rows x 128B, 8 insts/wave, pre-swizzled source ----
    const unsigned short* kbase =
        qkvb + (size_t)(b * NN + jh * 256) * QKV3 + INNER + h * DH;
#pragma unroll
    for (int i = 0; i < 8; ++i) {
        const int r = (w * 8 + i) * 8 + (l >> 3);   // row this lane covers
        const int c = (l & 7) ^ (r & 7);            // inverse-swizzled chunk
        __builtin_amdgcn_global_load_lds(
            (const AS1 void*)(kbase + (size_t)r * QKV3 + c * 8),
            (AS3 void*)(Ks + (w * 8 + i) * 512), 16, 0, 0);
    }

    const unsigned short* qb = qkvb + (size_t)(b * NN) * QKV3 + h * DH + lq * 8;
    const short8 qf0 = *(const short8*)(qb + (size_t)(i0 + lrow) * QKV3);
    const short8 qf1 = *(const short8*)(qb + (size_t)(i0 + lrow) * QKV3 + 32);

    asm volatile("s_waitcnt vmcnt(0)" ::: "memory");
    __syncthreads();

    unsigned short* obase = attnb + (size_t)bh * PSTR + (size_t)i0 * NN + jh * 256;
    const int sw = lrow & 7;                     // per-lane read swizzle
    float lacc = 0.f;
#pragma unroll
    for (int jt = 0; jt < 16; ++jt) {
        const int R = jt * 16 + lrow;
        const short8 kf0 = *(const short8*)(Ks + R * 64 + ((lq ^ sw) * 8));
        const short8 kf1 = *(const short8*)(Ks + R * 64 + (((4 + lq) ^ sw) * 8));
        f32x4 acc = (f32x4){0.f, 0.f, 0.f, 0.f};
        acc = __builtin_amdgcn_mfma_f32_16x16x32_bf16(kf0, qf0, acc, 0, 0, 0);
        acc = __builtin_amdgcn_mfma_f32_16x16x32_bf16(kf1, qf1, acc, 0, 0, 0);
        float e0 = __expf(acc[0] * 0.125f);
        float e1 = __expf(acc[1] * 0.125f);
        float e2 = __expf(acc[2] * 0.125f);
        float e3 = __expf(acc[3] * 0.125f);
        lacc += (e0 + e1) + (e2 + e3);
        ushort4 o;
        o.x = f2bf(e0); o.y = f2bf(e1); o.z = f2bf(e2); o.w = f2bf(e3);
        *(ushort4*)(&obuf[w][lrow][(jt & 3) * 16 + lq * 4]) = o;
        if ((jt & 3) == 3) {
            const int jb = (jt >> 2) * 64;
#pragma unroll
            for (int q = 0; q < 4; ++q) {
                const int rr = q * 4 + (l >> 4);
                const int cc = l & 15;
                *(ushort4*)(obase + (size_t)rr * NN + jb + cc * 4) =
                    *(const ushort4*)(&obuf[w][rr][cc * 4]);
            }
        }
    }
    lacc += __shfl_xor(lacc, 16, 64);
    lacc += __shfl_xor(lacc, 32, 64);
    if (lq == 0)
        lsum2[(size_t)jh * BB * HH * NN + (size_t)bh * NN + i0 + lrow] = lacc;
}

// ---------------------------------------------------------------------------
// Re-attention + LN over heads, bf16 in/out (fp32 math), 4 j per thread.
// ---------------------------------------------------------------------------
__global__ void reattn_ln_bf(unsigned short* __restrict__ attnb,
                             const float* __restrict__ lsum2,
                             const float* __restrict__ rw,
                             const float* __restrict__ gamma,
                             const float* __restrict__ beta) {
    __shared__ float w[16][16];
    __shared__ float gs[16], bs[16];
    const int tid = threadIdx.x;
    ((float*)w)[tid] = rw[tid];
    if (tid < 16) { gs[tid] = gamma[tid]; bs[tid] = beta[tid]; }
    __syncthreads();

    const size_t idx = (size_t)blockIdx.x * 256 + tid;  // over B*N*N/4
    const int j4 = (int)(idx & 127);
    const int i = (int)((idx >> 7) & 511);
    const int b = (int)(idx >> 16);
    unsigned short* base = attnb + (size_t)(b * HH) * PSTR + (size_t)i * NN + j4 * 4;
    const float* l0 = lsum2 + (size_t)(b * HH) * NN + i;
    const float* l1 = l0 + (size_t)BB * HH * NN;

    float v[16][4];
#pragma unroll
    for (int h = 0; h < 16; ++h) {
        const float linv = 1.0f / (l0[h * NN] + l1[h * NN]);
        ushort4 u = *(const ushort4*)(base + (size_t)h * PSTR);
        v[h][0] = bf2f(u.x) * linv; v[h][1] = bf2f(u.y) * linv;
        v[h][2] = bf2f(u.z) * linv; v[h][3] = bf2f(u.w) * linv;
    }
    float o[16][4];
    float me[4] = {0.f, 0.f, 0.f, 0.f};
#pragma unroll
    for (int g = 0; g < 16; ++g) {
        float s0 = 0.f, s1 = 0.f, s2 = 0.f, s3 = 0.f;
#pragma unroll
        for (int h = 0; h < 16; ++h) {
            const float wg = w[h][g];
            s0 += v[h][0] * wg; s1 += v[h][1] * wg;
            s2 += v[h][2] * wg; s3 += v[h][3] * wg;
        }
        o[g][0] = s0; o[g][1] = s1; o[g][2] = s2; o[g][3] = s3;
        me[0] += s0; me[1] += s1; me[2] += s2; me[3] += s3;
    }
#pragma unroll
    for (int r = 0; r < 4; ++r) me[r] *= 0.0625f;
    float va[4] = {0.f, 0.f, 0.f, 0.f};
#pragma unroll
    for (int g = 0; g < 16; ++g)
#pragma unroll
        for (int r = 0; r < 4; ++r) {
            float d = o[g][r] - me[r];
            va[r] += d * d;
        }
    float ri[4];
#pragma unroll
    for (int r = 0; r < 4; ++r) ri[r] = rsqrtf(va[r] * 0.0625f + 1e-3f);
#pragma unroll
    for (int g = 0; g < 16; ++g) {
        ushort4 u;
        u.x = f2bf((o[g][0] - me[0]) * ri[0] * gs[g] + bs[g]);
        u.y = f2bf((o[g][1] - me[1]) * ri[1] * gs[g] + bs[g]);
        u.z = f2bf((o[g][2] - me[2]) * ri[2] * gs[g] + bs[g]);
        u.w = f2bf((o[g][3] - me[3]) * ri[3] * gs[g] + bs[g]);
        *(ushort4*)(base + (size_t)g * PSTR) = u;
    }
}

// ---------------------------------------------------------------------------
// V transpose: qkvb [b,j,2048+h*64+d] -> vT [bh, d, j] (bf16)
// ---------------------------------------------------------------------------
__global__ void transpose_v(const unsigned short* __restrict__ qkvb,
                            unsigned short* __restrict__ vT) {
    __shared__ unsigned short t[32][33];
    const int bh = blockIdx.z;
    const int h = bh & 15, b = bh >> 4;
    const int j0 = blockIdx.x * 32, d0 = blockIdx.y * 32;
    const int tx = threadIdx.x & 31, ty = threadIdx.x >> 5;
    const unsigned short* src = qkvb + (size_t)(b * NN) * QKV3 + 2 * INNER + h * DH;
#pragma unroll
    for (int k = 0; k < 4; ++k)
        t[ty + 8 * k][tx] = src[(size_t)(j0 + ty + 8 * k) * QKV3 + d0 + tx];
    __syncthreads();
    unsigned short* dst = vT + (size_t)bh * DH * NN;
#pragma unroll
    for (int k = 0; k < 4; ++k)
        dst[(size_t)(d0 + ty + 8 * k) * NN + j0 + tx] = t[tx][ty + 8 * k];
}

// ---------------------------------------------------------------------------
// PV MFMA v2 (R12): 1-barrier-per-j-step dbuf (same schedule as the GEMMs).
// Stage P/V(js+1) -> slot s^1 first, read all 12 frags of slot s, lgkm0 +
// sched_barrier, 16-MFMA setprio cluster, vmcnt(0), single s_barrier.
// LDS: 2 x (Ps 16KB + Vs 8KB) = 48KB -> 2-3 blocks/CU.
// XCD-locality grid (R9): bh = blockIdx.x.
// ---------------------------------------------------------------------------
__device__ __forceinline__ void stage_pv(const unsigned short* __restrict__ pb,
                                         const unsigned short* __restrict__ vb,
                                         int j0, short* Ps, short* Vs,
                                         int w, int l, int lr8, int swd) {
#pragma unroll
    for (int t = 0; t < 4; ++t) {
        int c = w * 4 + t;
        int r = c * 8 + lr8;
        __builtin_amdgcn_global_load_lds(
            (const AS1 void*)(pb + (size_t)r * NN + j0 + swd),
            (AS3 void*)(Ps + c * 512), 16, 0, 0);
    }
#pragma unroll
    for (int t = 0; t < 2; ++t) {
        int c = w * 2 + t;
        int d = c * 8 + lr8;
        __builtin_amdgcn_global_load_lds(
            (const AS1 void*)(vb + (size_t)d * NN + j0 + swd),
            (AS3 void*)(Vs + c * 512), 16, 0, 0);
    }
}

__global__ __launch_bounds__(256) void pv_mfma(
    const unsigned short* __restrict__ attnb, const unsigned short* __restrict__ vT,
    unsigned short* __restrict__ outhb) {
    const int bh = blockIdx.x;
    const int h = bh & 15, b = bh >> 4;
    const int i0 = blockIdx.y * 128;
    __shared__ __align__(16) short Ps[2][128 * 64];   // 32KB
    __shared__ __align__(16) short Vs[2][64 * 64];    // 16KB
    const int tid = threadIdx.x;
    const int w = tid >> 6, l = tid & 63;
    const int lrow = l & 15, lq = l >> 4;
    const int lr8 = l >> 3;
    const int swd = ((l & 7) ^ (lr8 & 7)) * 8;

    f32x4 acc[2][4];
#pragma unroll
    for (int ic = 0; ic < 2; ++ic)
#pragma unroll
        for (int dt = 0; dt < 4; ++dt) acc[ic][dt] = (f32x4){0.f, 0.f, 0.f, 0.f};

    const unsigned short* pb = attnb + (size_t)bh * PSTR + (size_t)i0 * NN;
    const unsigned short* vb = vT + (size_t)bh * DH * NN;

    stage_pv(pb, vb, 0, Ps[0], Vs[0], w, l, lr8, swd);
    asm volatile("s_waitcnt vmcnt(0)" ::: "memory");
    __builtin_amdgcn_s_barrier();

    for (int js = 0; js < 8; ++js) {
        const int s = js & 1;
        if (js + 1 < 8)
            stage_pv(pb, vb, (js + 1) * 64, Ps[s ^ 1], Vs[s ^ 1], w, l, lr8, swd);

        short8 vf[8], pf[4];
#pragma unroll
        for (int kh = 0; kh < 2; ++kh) {
#pragma unroll
            for (int dt = 0; dt < 4; ++dt)
                vf[kh * 4 + dt] = *(const short8*)(
                    &Vs[s][(dt * 16 + lrow) * 64 + (((kh * 4 + lq) ^ (lrow & 7)) * 8)]);
#pragma unroll
            for (int ic = 0; ic < 2; ++ic)
                pf[kh * 2 + ic] = *(const short8*)(
                    &Ps[s][(w * 32 + ic * 16 + lrow) * 64 + (((kh * 4 + lq) ^ (lrow & 7)) * 8)]);
        }

        asm volatile("s_waitcnt lgkmcnt(0)" ::: "memory");
        __builtin_amdgcn_sched_barrier(0);

        __builtin_amdgcn_s_setprio(1);
#pragma unroll
        for (int kh = 0; kh < 2; ++kh)
#pragma unroll
            for (int ic = 0; ic < 2; ++ic)
#pragma unroll
                for (int dt = 0; dt < 4; ++dt)
                    acc[ic][dt] = __builtin_amdgcn_mfma_f32_16x16x32_bf16(
                        vf[kh * 4 + dt], pf[kh * 2 + ic], acc[ic][dt], 0, 0, 0);
        __builtin_amdgcn_s_setprio(0);

        asm volatile("s_waitcnt vmcnt(0)" ::: "memory");
        __builtin_amdgcn_s_barrier();
    }

#pragma unroll
    for (int ic = 0; ic < 2; ++ic) {
        unsigned short* orow = outhb +
            ((size_t)(b * NN + i0 + w * 32 + ic * 16 + lrow)) * INNER + h * DH + lq * 4;
#pragma unroll
        for (int dt = 0; dt < 4; ++dt) {
            ushort4 o;
            o.x = f2bf(acc[ic][dt][0]); o.y = f2bf(acc[ic][dt][1]);
            o.z = f2bf(acc[ic][dt][2]); o.w = f2bf(acc[ic][dt][3]);
            *(ushort4*)(orow + dt * 16) = o;
        }
    }
}

// ---------------------------------------------------------------------------
extern "C" void kernel_launch(void* const* d_in, const int* in_sizes, int n_in,
                              void* d_out, int out_size, void* d_ws, size_t ws_size,
                              hipStream_t stream) {
    const float* x        = (const float*)d_in[0];
    const float* w_qkv    = (const float*)d_in[1];
    const float* reattn_w = (const float*)d_in[2];
    const float* ln_gamma = (const float*)d_in[3];
    const float* ln_beta  = (const float*)d_in[4];
    const float* w_out    = (const float*)d_in[5];
    const float* b_out    = (const float*)d_in[6];
    float* out = (float*)d_out;

    unsigned short* qkvb  = (unsigned short*)d_ws;                 // 12.58M
    unsigned short* attnb = qkvb + (size_t)BB * NN * QKV3;         // 128 * PSTR
    unsigned short* vTb   = attnb + (size_t)BB * HH * PSTR;        // 4.19M
    unsigned short* outhb = vTb + (size_t)BB * HH * DH * NN;       // 4.19M
    unsigned short* xb    = outhb + (size_t)BB * NN * INNER;       // 4.19M
    unsigned short* wqkvT = xb + (size_t)BB * NN * DD;             // 3.15M
    unsigned short* woutT = wqkvT + (size_t)DD * QKV3;             // 1.05M
    float*          lsum2 = (float*)(woutT + (size_t)INNER * INNER);  // 2*B*H*N f32

    dim3 blk(256);

    // merged conversions (1 launch instead of 3)
    preprocess<<<dim3(8192), blk, 0, stream>>>(x, xb, w_qkv, wqkvT, w_out, woutT);

    // QKV projection -> bf16 (256^2-tile, 1-barrier-per-K-tile, 512 threads)
    gemm256_bf<<<dim3(QKV3 / 256, (BB * NN) / 256), dim3(512), 0, stream>>>(
        xb, wqkvT, qkvb, BB * NN, QKV3, DD);

    // streaming scores: unnormalized exp -> attn bf16 (padded planes)
    // XCD-locality grid: bh fastest so same-head blocks share an XCD L2
    scores_stream<<<dim3(BB * HH, 2, NN / 64), blk, 0, stream>>>(qkvb, attnb, lsum2);

    // re-attention + LN (normalizes by 1/(l0+l1) on load, in-place bf16)
    reattn_ln_bf<<<dim3((BB * NN * NN) / 1024), blk, 0, stream>>>(
        attnb, lsum2, reattn_w, ln_gamma, ln_beta);

    // V transpose -> [bh][d][j]
    transpose_v<<<dim3(NN / 32, DH / 32, BB * HH), blk, 0, stream>>>(qkvb, vTb);

    // P @ V -> outh bf16 (bh fastest for vT L2 locality; 1-barrier dbuf)
    pv_mfma<<<dim3(BB * HH, NN / 128), blk, 0, stream>>>(attnb, vTb, outhb);

    // output projection + bias (fp32 out; 1-barrier dbuf)
    gemm_bf16<<<dim3(INNER / 128, (BB * NN) / 128), blk, 0, stream>>>(
        outhb, woutT, out, b_out, BB * NN, INNER, INNER);
}

// Round 8
// 200.382 us; speedup vs baseline: 1.2240x; 1.0402x over previous
//
#include <hip/hip_runtime.h>
#include <math.h>

#define BB 8
#define NN 512
#define DD 1024
#define HH 16
#define DH 64
#define INNER 1024
#define QKV3 3072
// attn head-plane stride in shorts: N*N + 64 (128B pad) breaks the exact
// 512KB power-of-2 stride that aliases all 16 head planes onto the same
// L2-set/HBM-channel group in reattn_ln_bf's 16-plane gather.
#define PSTR (NN * NN + 64)

typedef __attribute__((ext_vector_type(8))) short short8;
typedef __attribute__((ext_vector_type(4))) float f32x4;

#define AS1 __attribute__((address_space(1)))
#define AS3 __attribute__((address_space(3)))

__device__ __forceinline__ float4 ld4(const float* p) { return *(const float4*)p; }

__device__ __forceinline__ unsigned short f2bf(float f) {
    unsigned u = __float_as_uint(f);
    return (unsigned short)((u + 0x7fffu + ((u >> 16) & 1u)) >> 16);
}
__device__ __forceinline__ float bf2f(unsigned short u) {
    return __uint_as_float(((unsigned)u) << 16);
}

// ---------------------------------------------------------------------------
// Merged preprocessing: conv_bf16 + convT(w_qkv) + convT(w_out) in one launch.
// ---------------------------------------------------------------------------
__global__ void preprocess(const float* __restrict__ x, unsigned short* __restrict__ xb,
                           const float* __restrict__ wq, unsigned short* __restrict__ wqT,
                           const float* __restrict__ wo, unsigned short* __restrict__ woT) {
    __shared__ float t[32][33];
    const int tid = threadIdx.x;
    const int bx = blockIdx.x;
    if (bx < 4096) {
        size_t i = ((size_t)bx * 256 + tid) * 4;
        float4 v = ld4(x + i);
        ushort4 o;
        o.x = f2bf(v.x); o.y = f2bf(v.y); o.z = f2bf(v.z); o.w = f2bf(v.w);
        *(ushort4*)(xb + i) = o;
        return;
    }
    const float* in; unsigned short* out; int K, N, n0, k0;
    if (bx < 7168) {
        const int bb = bx - 4096;
        in = wq; out = wqT; K = DD; N = QKV3;
        n0 = (bb % 96) * 32; k0 = (bb / 96) * 32;
    } else {
        const int bb = bx - 7168;
        in = wo; out = woT; K = INNER; N = INNER;
        n0 = (bb & 31) * 32; k0 = (bb >> 5) * 32;
    }
    const int tx = tid & 31, ty = tid >> 5;  // 32 x 8
#pragma unroll
    for (int l = 0; l < 4; ++l)
        t[ty + 8 * l][tx] = in[(size_t)(k0 + ty + 8 * l) * N + n0 + tx];
    __syncthreads();
#pragma unroll
    for (int l = 0; l < 4; ++l)
        out[(size_t)(n0 + ty + 8 * l) * K + k0 + tx] = f2bf(t[tx][ty + 8 * l]);
}

// ---------------------------------------------------------------------------
// bf16 MFMA GEMM, fp32 out (+bias): C[M,N] = A[M,K] * Bt[N,K]^T   (128x128)
// 1-barrier-per-K-tile dbuf (R7-verified).  LDS 32KB.
// ---------------------------------------------------------------------------
__device__ __forceinline__ void stage128(const unsigned short* __restrict__ A,
                                         const unsigned short* __restrict__ Bt,
                                         int K, int bm, int bn, int kt,
                                         short* sb, int w, int l) {
#pragma unroll
    for (int t = 0; t < 2; ++t) {
        const int q = w * 2 + t;
        const int li = q * 512 + l * 8;
        const int row = li >> 5, kc = li & 31;
        __builtin_amdgcn_global_load_lds(
            (const AS1 void*)(A + (size_t)(bm + row) * K + kt * 32 + kc),
            (AS3 void*)(sb + q * 512), 16, 0, 0);
        __builtin_amdgcn_global_load_lds(
            (const AS1 void*)(Bt + (size_t)(bn + row) * K + kt * 32 + kc),
            (AS3 void*)(sb + 4096 + q * 512), 16, 0, 0);
    }
}

__global__ __launch_bounds__(256) void gemm_bf16(
    const unsigned short* __restrict__ A, const unsigned short* __restrict__ Bt,
    float* __restrict__ C, const float* __restrict__ bias, int M, int N, int K) {
    __shared__ __align__(16) short lds_[2 * 8192];   // 32KB
    const int tid = threadIdx.x;
    const int w = tid >> 6, l = tid & 63;
    const int bm = blockIdx.y * 128, bn = blockIdx.x * 128;
    const int wm = (w >> 1) * 64, wn = (w & 1) * 64;
    const int lrow = l & 15, lq = l >> 4;
    const int NT = K >> 5;

    f32x4 acc[4][4];
#pragma unroll
    for (int i = 0; i < 4; ++i)
#pragma unroll
        for (int j = 0; j < 4; ++j) acc[i][j] = (f32x4){0.f, 0.f, 0.f, 0.f};

    stage128(A, Bt, K, bm, bn, 0, lds_, w, l);
    asm volatile("s_waitcnt vmcnt(0)" ::: "memory");
    __builtin_amdgcn_s_barrier();

    for (int t = 0; t < NT; ++t) {
        const int s = t & 1;
        if (t + 1 < NT)
            stage128(A, Bt, K, bm, bn, t + 1, lds_ + (s ^ 1) * 8192, w, l);
        const short* As_ = lds_ + s * 8192;
        const short* Bs_ = As_ + 4096;
        short8 a[4], b[4];
#pragma unroll
        for (int i = 0; i < 4; ++i)
            a[i] = *(const short8*)(As_ + (wm + i * 16 + lrow) * 32 + lq * 8);
#pragma unroll
        for (int j = 0; j < 4; ++j)
            b[j] = *(const short8*)(Bs_ + (wn + j * 16 + lrow) * 32 + lq * 8);

        asm volatile("s_waitcnt lgkmcnt(0)" ::: "memory");
        __builtin_amdgcn_sched_barrier(0);

        __builtin_amdgcn_s_setprio(1);
#pragma unroll
        for (int i = 0; i < 4; ++i)
#pragma unroll
            for (int j = 0; j < 4; ++j)
                acc[i][j] = __builtin_amdgcn_mfma_f32_16x16x32_bf16(a[i], b[j], acc[i][j], 0, 0, 0);
        __builtin_amdgcn_s_setprio(0);

        asm volatile("s_waitcnt vmcnt(0)" ::: "memory");
        __builtin_amdgcn_s_barrier();
    }

#pragma unroll
    for (int i = 0; i < 4; ++i)
#pragma unroll
        for (int j = 0; j < 4; ++j) {
            const int col = bn + wn + j * 16 + lrow;
            const float bv = bias ? bias[col] : 0.f;
#pragma unroll
            for (int r = 0; r < 4; ++r) {
                const int row = bm + wm + i * 16 + lq * 4 + r;
                C[(size_t)row * N + col] = acc[i][j][r] + bv;
            }
        }
}

// ---------------------------------------------------------------------------
// QKV GEMM v3 (R13): 256x128-tile, bf16 out. Same R6-proven 1-barrier dbuf
// schedule, but grid = 24x16 = 384 blocks (was 192 at 256^2: 25% of CUs sat
// idle and the vmcnt(0) drain was fully exposed at 1 block/CU). LDS/slot =
// A 256x32 + B 128x32 = 24KB -> 48KB total -> 2 co-resident blocks/CU: one
// block's MFMA covers the other's drain. 8 waves as 4M x 2N, per-wave 64x64
// (acc[4][4], half the old register pressure).
// Subtiles: 16rx32c, 512 shorts; A subtiles 0-15 at s*512, B at 8192+s*512.
// ---------------------------------------------------------------------------
__device__ __forceinline__ void stage_st(const unsigned short* __restrict__ G, int K,
                                         int row0, int kt, short* dst_half,
                                         int w, int l) {
    const int grow = row0 + w * 16 + (l >> 2);
    const int gcol = kt * 32 + (((l & 3) * 8) ^ ((l & 32) ? 16 : 0));
    __builtin_amdgcn_global_load_lds(
        (const AS1 void*)(G + (size_t)grow * K + gcol),
        (AS3 void*)(dst_half + w * 512), 16, 0, 0);
}

__global__ __launch_bounds__(512, 4) void gemm256_bf(
    const unsigned short* __restrict__ A, const unsigned short* __restrict__ Bt,
    unsigned short* __restrict__ C, int M, int N, int K) {
    __shared__ __align__(16) short lds_[2 * 12288];   // 48KB
    const int tid = threadIdx.x;
    const int w = tid >> 6, l = tid & 63;
    const int wmi = w >> 1, wni = w & 1;        // 4M x 2N wave grid
    const int lrow = l & 15, lq = l >> 4;
    const int bm = blockIdx.y * 256, bn = blockIdx.x * 128;
    const int NT = K >> 5;                       // K-tiles of 32

    const int aoff = lrow * 32 + ((lq * 8) ^ ((lrow & 8) ? 16 : 0));

    f32x4 acc[4][4];
#pragma unroll
    for (int i = 0; i < 4; ++i)
#pragma unroll
        for (int j = 0; j < 4; ++j) acc[i][j] = (f32x4){0.f, 0.f, 0.f, 0.f};

    // ---- prologue: tile 0 into slot 0 ----
    stage_st(A,  K, bm,       0, lds_ + 0,    w, l);
    stage_st(A,  K, bm + 128, 0, lds_ + 4096, w, l);
    stage_st(Bt, K, bn,       0, lds_ + 8192, w, l);
    asm volatile("s_waitcnt vmcnt(0)" ::: "memory");
    __builtin_amdgcn_s_barrier();

    for (int t = 0; t < NT; ++t) {
        const int s = t & 1;
        if (t + 1 < NT) {
            short* nb = lds_ + (s ^ 1) * 12288;
            stage_st(A,  K, bm,       t + 1, nb,        w, l);
            stage_st(A,  K, bm + 128, t + 1, nb + 4096, w, l);
            stage_st(Bt, K, bn,       t + 1, nb + 8192, w, l);
        }
        const short* cb = lds_ + s * 12288;
        short8 a[4], b[4];
#pragma unroll
        for (int i = 0; i < 4; ++i)
            a[i] = *(const short8*)(cb + (wmi * 4 + i) * 512 + aoff);
#pragma unroll
        for (int j = 0; j < 4; ++j)
            b[j] = *(const short8*)(cb + 8192 + (wni * 4 + j) * 512 + aoff);

        asm volatile("s_waitcnt lgkmcnt(0)" ::: "memory");
        __builtin_amdgcn_sched_barrier(0);   // rule #18: pin MFMA below the wait

        __builtin_amdgcn_s_setprio(1);
#pragma unroll
        for (int i = 0; i < 4; ++i)
#pragma unroll
            for (int j = 0; j < 4; ++j)
                acc[i][j] = __builtin_amdgcn_mfma_f32_16x16x32_bf16(a[i], b[j], acc[i][j], 0, 0, 0);
        __builtin_amdgcn_s_setprio(0);

        asm volatile("s_waitcnt vmcnt(0)" ::: "memory");
        __builtin_amdgcn_s_barrier();
    }

    // ---- epilogue: bf16 C ----
#pragma unroll
    for (int i = 0; i < 4; ++i)
#pragma unroll
        for (int j = 0; j < 4; ++j) {
            const int col = bn + wni * 64 + j * 16 + lrow;
#pragma unroll
            for (int r = 0; r < 4; ++r) {
                const int row = bm + wmi * 64 + i * 16 + lq * 4 + r;
                C[(size_t)row * N + col] = f2bf(acc[i][j][r]);
            }
        }
}

// ---------------------------------------------------------------------------
// Merged scores + V-transpose (R13): both depend only on qkvb -> one launch
// (7 -> 6 graph nodes). 1-D grid 6144: [0,2048) scores, [2048,6144) transpose.
// Scores branch = R6-verified v3 (K-half LDS-staged via global_load_lds with
// XOR-preswizzled source, coalesced obuf flush, XCD-locality bh-fastest).
// LDS union: one pool, scores uses [0,16384)+[16384,20736); transpose uses
// its own 32x33 view of the pool.
// ---------------------------------------------------------------------------
__global__ __launch_bounds__(256) void scores_tv(
    const unsigned short* __restrict__ qkvb, unsigned short* __restrict__ attnb,
    unsigned short* __restrict__ vT, float* __restrict__ lsum2) {
    __shared__ unsigned short sh[256 * 64 + 4 * 16 * 68];   // 41.2KB pool
    const int bx = blockIdx.x;
    const int tid = threadIdx.x;

    if (bx >= 2048) {
        // ---- V transpose: qkvb [b,j,2048+h*64+d] -> vT [bh, d, j] ----
        const int t = bx - 2048;
        const int j0 = (t & 15) * 32;
        const int d0 = ((t >> 4) & 1) * 32;
        const int bh = t >> 5;
        const int h = bh & 15, b = bh >> 4;
        unsigned short (*tt)[33] = (unsigned short(*)[33])sh;
        const int tx = tid & 31, ty = tid >> 5;
        const unsigned short* src = qkvb + (size_t)(b * NN) * QKV3 + 2 * INNER + h * DH;
#pragma unroll
        for (int k = 0; k < 4; ++k)
            tt[ty + 8 * k][tx] = src[(size_t)(j0 + ty + 8 * k) * QKV3 + d0 + tx];
        __syncthreads();
        unsigned short* dst = vT + (size_t)bh * DH * NN;
#pragma unroll
        for (int k = 0; k < 4; ++k)
            dst[(size_t)(d0 + ty + 8 * k) * NN + j0 + tx] = tt[tx][ty + 8 * k];
        return;
    }

    // ---- scores branch ----
    unsigned short* Ks = sh;                          // [256*64]
    unsigned short* obuf = sh + 16384;                // [4][16][68]
    const int bh = bx & 127;
    const int h = bh & 15, b = bh >> 4;
    const int jh = (bx >> 7) & 1;
    const int w = tid >> 6, l = tid & 63;
    const int i0 = (bx >> 8) * 64 + w * 16;
    const int lrow = l & 15, lq = l >> 4;

    const unsigned short* kbase =
        qkvb + (size_t)(b * NN + jh * 256) * QKV3 + INNER + h * DH;
#pragma unroll
    for (int i = 0; i < 8; ++i) {
        const int r = (w * 8 + i) * 8 + (l >> 3);   // row this lane covers
        const int c = (l & 7) ^ (r & 7);            // inverse-swizzled chunk
        __builtin_amdgcn_global_load_lds(
            (const AS1 void*)(kbase + (size_t)r * QKV3 + c * 8),
            (AS3 void*)(Ks + (w * 8 + i) * 512), 16, 0, 0);
    }

    const unsigned short* qb = qkvb + (size_t)(b * NN) * QKV3 + h * DH + lq * 8;
    const short8 qf0 = *(const short8*)(qb + (size_t)(i0 + lrow) * QKV3);
    const short8 qf1 = *(const short8*)(qb + (size_t)(i0 + lrow) * QKV3 + 32);

    asm volatile("s_waitcnt vmcnt(0)" ::: "memory");
    __syncthreads();

    unsigned short* obase = attnb + (size_t)bh * PSTR + (size_t)i0 * NN + jh * 256;
    unsigned short* ob = obuf + (w * 16) * 68;
    const int sw = lrow & 7;                     // per-lane read swizzle
    float lacc = 0.f;
#pragma unroll
    for (int jt = 0; jt < 16; ++jt) {
        const int R = jt * 16 + lrow;
        const short8 kf0 = *(const short8*)(Ks + R * 64 + ((lq ^ sw) * 8));
        const short8 kf1 = *(const short8*)(Ks + R * 64 + (((4 + lq) ^ sw) * 8));
        f32x4 acc = (f32x4){0.f, 0.f, 0.f, 0.f};
        acc = __builtin_amdgcn_mfma_f32_16x16x32_bf16(kf0, qf0, acc, 0, 0, 0);
        acc = __builtin_amdgcn_mfma_f32_16x16x32_bf16(kf1, qf1, acc, 0, 0, 0);
        float e0 = __expf(acc[0] * 0.125f);
        float e1 = __expf(acc[1] * 0.125f);
        float e2 = __expf(acc[2] * 0.125f);
        float e3 = __expf(acc[3] * 0.125f);
        lacc += (e0 + e1) + (e2 + e3);
        ushort4 o;
        o.x = f2bf(e0); o.y = f2bf(e1); o.z = f2bf(e2); o.w = f2bf(e3);
        *(ushort4*)(ob + lrow * 68 + (jt & 3) * 16 + lq * 4) = o;
        if ((jt & 3) == 3) {
            const int jb = (jt >> 2) * 64;
#pragma unroll
            for (int q = 0; q < 4; ++q) {
                const int rr = q * 4 + (l >> 4);
                const int cc = l & 15;
                *(ushort4*)(obase + (size_t)rr * NN + jb + cc * 4) =
                    *(const ushort4*)(ob + rr * 68 + cc * 4);
            }
        }
    }
    lacc += __shfl_xor(lacc, 16, 64);
    lacc += __shfl_xor(lacc, 32, 64);
    if (lq == 0)
        lsum2[(size_t)jh * BB * HH * NN + (size_t)bh * NN + i0 + lrow] = lacc;
}

// ---------------------------------------------------------------------------
// Re-attention + LN over heads, bf16 in/out (fp32 math), 4 j per thread.
// ---------------------------------------------------------------------------
__global__ void reattn_ln_bf(unsigned short* __restrict__ attnb,
                             const float* __restrict__ lsum2,
                             const float* __restrict__ rw,
                             const float* __restrict__ gamma,
                             const float* __restrict__ beta) {
    __shared__ float w[16][16];
    __shared__ float gs[16], bs[16];
    const int tid = threadIdx.x;
    ((float*)w)[tid] = rw[tid];
    if (tid < 16) { gs[tid] = gamma[tid]; bs[tid] = beta[tid]; }
    __syncthreads();

    const size_t idx = (size_t)blockIdx.x * 256 + tid;  // over B*N*N/4
    const int j4 = (int)(idx & 127);
    const int i = (int)((idx >> 7) & 511);
    const int b = (int)(idx >> 16);
    unsigned short* base = attnb + (size_t)(b * HH) * PSTR + (size_t)i * NN + j4 * 4;
    const float* l0 = lsum2 + (size_t)(b * HH) * NN + i;
    const float* l1 = l0 + (size_t)BB * HH * NN;

    float v[16][4];
#pragma unroll
    for (int h = 0; h < 16; ++h) {
        const float linv = 1.0f / (l0[h * NN] + l1[h * NN]);
        ushort4 u = *(const ushort4*)(base + (size_t)h * PSTR);
        v[h][0] = bf2f(u.x) * linv; v[h][1] = bf2f(u.y) * linv;
        v[h][2] = bf2f(u.z) * linv; v[h][3] = bf2f(u.w) * linv;
    }
    float o[16][4];
    float me[4] = {0.f, 0.f, 0.f, 0.f};
#pragma unroll
    for (int g = 0; g < 16; ++g) {
        float s0 = 0.f, s1 = 0.f, s2 = 0.f, s3 = 0.f;
#pragma unroll
        for (int h = 0; h < 16; ++h) {
            const float wg = w[h][g];
            s0 += v[h][0] * wg; s1 += v[h][1] * wg;
            s2 += v[h][2] * wg; s3 += v[h][3] * wg;
        }
        o[g][0] = s0; o[g][1] = s1; o[g][2] = s2; o[g][3] = s3;
        me[0] += s0; me[1] += s1; me[2] += s2; me[3] += s3;
    }
#pragma unroll
    for (int r = 0; r < 4; ++r) me[r] *= 0.0625f;
    float va[4] = {0.f, 0.f, 0.f, 0.f};
#pragma unroll
    for (int g = 0; g < 16; ++g)
#pragma unroll
        for (int r = 0; r < 4; ++r) {
            float d = o[g][r] - me[r];
            va[r] += d * d;
        }
    float ri[4];
#pragma unroll
    for (int r = 0; r < 4; ++r) ri[r] = rsqrtf(va[r] * 0.0625f + 1e-3f);
#pragma unroll
    for (int g = 0; g < 16; ++g) {
        ushort4 u;
        u.x = f2bf((o[g][0] - me[0]) * ri[0] * gs[g] + bs[g]);
        u.y = f2bf((o[g][1] - me[1]) * ri[1] * gs[g] + bs[g]);
        u.z = f2bf((o[g][2] - me[2]) * ri[2] * gs[g] + bs[g]);
        u.w = f2bf((o[g][3] - me[3]) * ri[3] * gs[g] + bs[g]);
        *(ushort4*)(base + (size_t)g * PSTR) = u;
    }
}

// ---------------------------------------------------------------------------
// PV MFMA: 1-barrier-per-j-step dbuf (R7-verified). LDS 48KB.
// XCD-locality grid: bh = blockIdx.x.
// ---------------------------------------------------------------------------
__device__ __forceinline__ void stage_pv(const unsigned short* __restrict__ pb,
                                         const unsigned short* __restrict__ vb,
                                         int j0, short* Ps, short* Vs,
                                         int w, int l, int lr8, int swd) {
#pragma unroll
    for (int t = 0; t < 4; ++t) {
        int c = w * 4 + t;
        int r = c * 8 + lr8;
        __builtin_amdgcn_global_load_lds(
            (const AS1 void*)(pb + (size_t)r * NN + j0 + swd),
            (AS3 void*)(Ps + c * 512), 16, 0, 0);
    }
#pragma unroll
    for (int t = 0; t < 2; ++t) {
        int c = w * 2 + t;
        int d = c * 8 + lr8;
        __builtin_amdgcn_global_load_lds(
            (const AS1 void*)(vb + (size_t)d * NN + j0 + swd),
            (AS3 void*)(Vs + c * 512), 16, 0, 0);
    }
}

__global__ __launch_bounds__(256) void pv_mfma(
    const unsigned short* __restrict__ attnb, const unsigned short* __restrict__ vT,
    unsigned short* __restrict__ outhb) {
    const int bh = blockIdx.x;
    const int h = bh & 15, b = bh >> 4;
    const int i0 = blockIdx.y * 128;
    __shared__ __align__(16) short Ps[2][128 * 64];   // 32KB
    __shared__ __align__(16) short Vs[2][64 * 64];    // 16KB
    const int tid = threadIdx.x;
    const int w = tid >> 6, l = tid & 63;
    const int lrow = l & 15, lq = l >> 4;
    const int lr8 = l >> 3;
    const int swd = ((l & 7) ^ (lr8 & 7)) * 8;

    f32x4 acc[2][4];
#pragma unroll
    for (int ic = 0; ic < 2; ++ic)
#pragma unroll
        for (int dt = 0; dt < 4; ++dt) acc[ic][dt] = (f32x4){0.f, 0.f, 0.f, 0.f};

    const unsigned short* pb = attnb + (size_t)bh * PSTR + (size_t)i0 * NN;
    const unsigned short* vb = vT + (size_t)bh * DH * NN;

    stage_pv(pb, vb, 0, Ps[0], Vs[0], w, l, lr8, swd);
    asm volatile("s_waitcnt vmcnt(0)" ::: "memory");
    __builtin_amdgcn_s_barrier();

    for (int js = 0; js < 8; ++js) {
        const int s = js & 1;
        if (js + 1 < 8)
            stage_pv(pb, vb, (js + 1) * 64, Ps[s ^ 1], Vs[s ^ 1], w, l, lr8, swd);

        short8 vf[8], pf[4];
#pragma unroll
        for (int kh = 0; kh < 2; ++kh) {
#pragma unroll
            for (int dt = 0; dt < 4; ++dt)
                vf[kh * 4 + dt] = *(const short8*)(
                    &Vs[s][(dt * 16 + lrow) * 64 + (((kh * 4 + lq) ^ (lrow & 7)) * 8)]);
#pragma unroll
            for (int ic = 0; ic < 2; ++ic)
                pf[kh * 2 + ic] = *(const short8*)(
                    &Ps[s][(w * 32 + ic * 16 + lrow) * 64 + (((kh * 4 + lq) ^ (lrow & 7)) * 8)]);
        }

        asm volatile("s_waitcnt lgkmcnt(0)" ::: "memory");
        __builtin_amdgcn_sched_barrier(0);

        __builtin_amdgcn_s_setprio(1);
#pragma unroll
        for (int kh = 0; kh < 2; ++kh)
#pragma unroll
            for (int ic = 0; ic < 2; ++ic)
#pragma unroll
                for (int dt = 0; dt < 4; ++dt)
                    acc[ic][dt] = __builtin_amdgcn_mfma_f32_16x16x32_bf16(
                        vf[kh * 4 + dt], pf[kh * 2 + ic], acc[ic][dt], 0, 0, 0);
        __builtin_amdgcn_s_setprio(0);

        asm volatile("s_waitcnt vmcnt(0)" ::: "memory");
        __builtin_amdgcn_s_barrier();
    }

#pragma unroll
    for (int ic = 0; ic < 2; ++ic) {
        unsigned short* orow = outhb +
            ((size_t)(b * NN + i0 + w * 32 + ic * 16 + lrow)) * INNER + h * DH + lq * 4;
#pragma unroll
        for (int dt = 0; dt < 4; ++dt) {
            ushort4 o;
            o.x = f2bf(acc[ic][dt][0]); o.y = f2bf(acc[ic][dt][1]);
            o.z = f2bf(acc[ic][dt][2]); o.w = f2bf(acc[ic][dt][3]);
            *(ushort4*)(orow + dt * 16) = o;
        }
    }
}

// ---------------------------------------------------------------------------
extern "C" void kernel_launch(void* const* d_in, const int* in_sizes, int n_in,
                              void* d_out, int out_size, void* d_ws, size_t ws_size,
                              hipStream_t stream) {
    const float* x        = (const float*)d_in[0];
    const float* w_qkv    = (const float*)d_in[1];
    const float* reattn_w = (const float*)d_in[2];
    const float* ln_gamma = (const float*)d_in[3];
    const float* ln_beta  = (const float*)d_in[4];
    const float* w_out    = (const float*)d_in[5];
    const float* b_out    = (const float*)d_in[6];
    float* out = (float*)d_out;

    unsigned short* qkvb  = (unsigned short*)d_ws;                 // 12.58M
    unsigned short* attnb = qkvb + (size_t)BB * NN * QKV3;         // 128 * PSTR
    unsigned short* vTb   = attnb + (size_t)BB * HH * PSTR;        // 4.19M
    unsigned short* outhb = vTb + (size_t)BB * HH * DH * NN;       // 4.19M
    unsigned short* xb    = outhb + (size_t)BB * NN * INNER;       // 4.19M
    unsigned short* wqkvT = xb + (size_t)BB * NN * DD;             // 3.15M
    unsigned short* woutT = wqkvT + (size_t)DD * QKV3;             // 1.05M
    float*          lsum2 = (float*)(woutT + (size_t)INNER * INNER);  // 2*B*H*N f32

    dim3 blk(256);

    // merged conversions (1 launch)
    preprocess<<<dim3(8192), blk, 0, stream>>>(x, xb, w_qkv, wqkvT, w_out, woutT);

    // QKV projection -> bf16 (256x128-tile, 384 blocks, 2 resident/CU)
    gemm256_bf<<<dim3(QKV3 / 128, (BB * NN) / 256), dim3(512), 0, stream>>>(
        xb, wqkvT, qkvb, BB * NN, QKV3, DD);

    // merged scores + V-transpose (both depend only on qkvb)
    scores_tv<<<dim3(6144), blk, 0, stream>>>(qkvb, attnb, vTb, lsum2);

    // re-attention + LN (normalizes by 1/(l0+l1) on load, in-place bf16)
    reattn_ln_bf<<<dim3((BB * NN * NN) / 1024), blk, 0, stream>>>(
        attnb, lsum2, reattn_w, ln_gamma, ln_beta);

    // P @ V -> outh bf16 (bh fastest for vT L2 locality; 1-barrier dbuf)
    pv_mfma<<<dim3(BB * HH, NN / 128), blk, 0, stream>>>(attnb, vTb, outhb);

    // output projection + bias (fp32 out; 1-barrier dbuf)
    gemm_bf16<<<dim3(INNER / 128, (BB * NN) / 128), blk, 0, stream>>>(
        outhb, woutT, out, b_out, BB * NN, INNER, INNER);
}